// Round 2
// baseline (494.888 us; speedup 1.0000x reference)
//
#include <hip/hip_runtime.h>
#include <stdint.h>

#define N_NODES 50000
#define N_EDGES 625000
#define DIN 256
#define HD 128
#define LN_EPS 1e-5f

typedef __attribute__((ext_vector_type(8))) short bvec8;
typedef __attribute__((ext_vector_type(4))) float fvec4;

__device__ inline float bf2f(ushort u){
  union { uint32_t u32; float f; } c; c.u32 = ((uint32_t)u) << 16; return c.f;
}
__device__ inline ushort f2bf(float f){
  union { float f; uint32_t u; } c; c.f = f;
  uint32_t u = c.u;
  return (ushort)((u + 0x7fffu + ((u >> 16) & 1u)) >> 16);
}
__device__ inline float rdany(const void* p, int i, int f32){
  return f32 ? ((const float*)p)[i] : bf2f(((const ushort*)p)[i]);
}

// ---------------- dtype probe ----------------
// bf16 storage of N(0,1): exponents cluster near 127, ~0 outliers.
// fp32 storage read as ushort: even halves are uniform mantissa bits -> ~45% crazy exponents.
__global__ void k_probe(const ushort* __restrict__ x, int* __restrict__ flag){
  __shared__ int red[256];
  int t = threadIdx.x;
  int c = 0;
  for (int j = 0; j < 8; j++){
    ushort u = x[t * 8 + j];
    int e = (u >> 7) & 0xff;
    if (e >= 0x88 || (e != 0 && e <= 0x70)) c++;
  }
  red[t] = c;
  __syncthreads();
  for (int off = 128; off > 0; off >>= 1){
    if (t < off) red[t] += red[t + off];
    __syncthreads();
  }
  if (t == 0) flag[0] = (red[0] > 100) ? 1 : 0;
}

// ---------------- CSR build ----------------
__global__ void k_zero(int* cnt, int* cursor){
  int i = blockIdx.x * 256 + threadIdx.x;
  if (i < N_NODES){ cnt[i] = 0; cursor[i] = 0; }
}

__global__ void k_count(const int* __restrict__ dst, int* __restrict__ cnt){
  int e = blockIdx.x * 256 + threadIdx.x;
  if (e < N_EDGES) atomicAdd(&cnt[dst[e]], 1);
}

__global__ void __launch_bounds__(1024) k_scan(const int* __restrict__ cnt, int* __restrict__ rowstart){
  __shared__ int sums[1024];
  int t = threadIdx.x;
  const int C = (N_NODES + 1023) / 1024;
  int b = t * C, e = b + C; if (e > N_NODES) e = N_NODES; if (b > N_NODES) b = N_NODES;
  int s = 0;
  for (int i = b; i < e; i++) s += cnt[i];
  sums[t] = s;
  __syncthreads();
  for (int off = 1; off < 1024; off <<= 1){
    int v = (t >= off) ? sums[t - off] : 0;
    __syncthreads();
    sums[t] += v;
    __syncthreads();
  }
  int pre = (t == 0) ? 0 : sums[t - 1];
  for (int i = b; i < e; i++){ rowstart[i] = pre; pre += cnt[i]; }
  if (t == 1023) rowstart[N_NODES] = sums[1023];
}

__global__ void k_fill(const int* __restrict__ src, const int* __restrict__ dst,
                       const int* __restrict__ rowstart, int* __restrict__ cursor,
                       int* __restrict__ esrc){
  int e = blockIdx.x * 256 + threadIdx.x;
  if (e < N_EDGES){
    int d = dst[e];
    int pos = atomicAdd(&cursor[d], 1);
    esrc[rowstart[d] + pos] = src[e];
  }
}

// ---------------- weight prep (dtype-adaptive) ----------------
__global__ void k_prep_w(const int* __restrict__ flag,
                         const void* __restrict__ W_in,
                         const void* __restrict__ Wl1, const void* __restrict__ Wr1,
                         const void* __restrict__ Wl2, const void* __restrict__ Wr2,
                         ushort* __restrict__ WtA, ushort* __restrict__ Wc1, ushort* __restrict__ Wc2){
  int f32 = flag[0];
  int idx = blockIdx.x * 256 + threadIdx.x;
  if (idx >= 128 * 256) return;
  int n = idx >> 8;
  int k = idx & 255;
  WtA[n * 256 + k] = f2bf(rdany(W_in, k * 128 + n, f32));
  if (k < 128){
    Wc1[n * 256 + k] = f2bf(rdany(Wl1, k * 128 + n, f32));
    Wc2[n * 256 + k] = f2bf(rdany(Wl2, k * 128 + n, f32));
  } else {
    Wc1[n * 256 + k] = f2bf(rdany(Wr1, (k - 128) * 128 + n, f32));
    Wc2[n * 256 + k] = f2bf(rdany(Wr2, (k - 128) * 128 + n, f32));
  }
}

// small vectors -> fp32 staging: b_in[0:128], kind_embed[128:512], ext_seed[512:640],
// bl1[640:768], gamma[768:896], beta[896:1024], bl2[1024:1152]
__global__ void k_prep_vec(const int* __restrict__ flag,
                           const void* b_in, const void* kind_embed, const void* ext_seed,
                           const void* bl1, const void* gammap, const void* betap,
                           const void* bl2, float* __restrict__ vecs){
  int f32 = flag[0];
  for (int i = threadIdx.x; i < 1152; i += 256){
    float v;
    if (i < 128)       v = rdany(b_in, i, f32);
    else if (i < 512)  v = rdany(kind_embed, i - 128, f32);
    else if (i < 640)  v = rdany(ext_seed, i - 512, f32);
    else if (i < 768)  v = rdany(bl1, i - 640, f32);
    else if (i < 896)  v = rdany(gammap, i - 768, f32);
    else if (i < 1024) v = rdany(betap, i - 896, f32);
    else               v = rdany(bl2, i - 1024, f32);
    vecs[i] = v;
  }
}

// ---------------- input GEMM ----------------
__global__ void __launch_bounds__(256) k_gemm_in(
    const int* __restrict__ flag, const void* __restrict__ xin,
    const ushort* __restrict__ WtA, const float* __restrict__ vecs,
    const int* __restrict__ node_kind, ushort* __restrict__ h0){
  int f32 = flag[0];
  int wave = threadIdx.x >> 6;
  int lane = threadIdx.x & 63;
  int quad = lane >> 4;
  int l16  = lane & 15;
  int rb = blockIdx.x * 64 + wave * 16;

  fvec4 acc[8];
  #pragma unroll
  for (int t = 0; t < 8; t++)
    #pragma unroll
    for (int i = 0; i < 4; i++) acc[t][i] = 0.f;

  int arow = rb + l16; if (arow >= N_NODES) arow = N_NODES - 1;
  const ushort* abf = (const ushort*)xin + (size_t)arow * DIN + quad * 8;
  const float*  af  = (const float*)xin + (size_t)arow * DIN + quad * 8;

  #pragma unroll
  for (int k0 = 0; k0 < DIN; k0 += 32){
    bvec8 a;
    if (f32){
      fvec4 lo = *(const fvec4*)(af + k0);
      fvec4 hi = *(const fvec4*)(af + k0 + 4);
      a[0] = (short)f2bf(lo[0]); a[1] = (short)f2bf(lo[1]);
      a[2] = (short)f2bf(lo[2]); a[3] = (short)f2bf(lo[3]);
      a[4] = (short)f2bf(hi[0]); a[5] = (short)f2bf(hi[1]);
      a[6] = (short)f2bf(hi[2]); a[7] = (short)f2bf(hi[3]);
    } else {
      a = *(const bvec8*)(abf + k0);
    }
    #pragma unroll
    for (int t = 0; t < 8; t++){
      bvec8 b = *(const bvec8*)(WtA + (t * 16 + l16) * DIN + k0 + quad * 8);
      acc[t] = __builtin_amdgcn_mfma_f32_16x16x32_bf16(a, b, acc[t], 0, 0, 0);
    }
  }

  const float* b_in  = vecs;
  const float* kinde = vecs + 128;
  const float* ext   = vecs + 512;
  #pragma unroll
  for (int i = 0; i < 4; i++){
    int row = rb + quad * 4 + i;
    if (row >= N_NODES) continue;
    int kind = node_kind[row];
    float extf = (kind != 0) ? 1.f : 0.f;
    #pragma unroll
    for (int t = 0; t < 8; t++){
      int col = t * 16 + l16;
      float v = acc[t][i] + b_in[col] + kinde[kind * HD + col] + extf * ext[col];
      h0[(size_t)row * HD + col] = f2bf(v);
    }
  }
}

// ---------------- mean aggregation (CSR walk, internal bf16) ----------------
__global__ void __launch_bounds__(256) k_gather(
    const ushort* __restrict__ h, const int* __restrict__ rowstart,
    const int* __restrict__ esrc, ushort* __restrict__ agg){
  int n = blockIdx.x * 4 + (threadIdx.x >> 6);
  int lane = threadIdx.x & 63;
  if (n >= N_NODES) return;
  int b = rowstart[n], e = rowstart[n + 1];
  float a0 = 0.f, a1 = 0.f;
  for (int i = b; i < e; i++){
    int s = esrc[i];
    uint32_t pv = *(const uint32_t*)(h + (size_t)s * HD + lane * 2);
    a0 += bf2f((ushort)(pv & 0xffffu));
    a1 += bf2f((ushort)(pv >> 16));
  }
  int deg = e - b;
  float scale = (deg > 0) ? 1.f / (float)deg : 0.f;
  a0 *= scale; a1 *= scale;
  uint32_t ov = (uint32_t)f2bf(a0) | ((uint32_t)f2bf(a1) << 16);
  *(uint32_t*)(agg + (size_t)n * HD + lane * 2) = ov;
}

// ---------------- conv GEMM: z = [agg|h] @ [Wl;Wr] + bias ----------------
// MODE1: +LN+ReLU -> bf16 h1.  MODE2: +bias -> d_out (dtype per flag).
template<int MODE>
__global__ void __launch_bounds__(256) k_conv(
    const int* __restrict__ flag,
    const ushort* __restrict__ agg, const ushort* __restrict__ h,
    const ushort* __restrict__ Wc, const float* __restrict__ vecs,
    void* __restrict__ outp){
  int f32 = flag[0];
  int wave = threadIdx.x >> 6;
  int lane = threadIdx.x & 63;
  int quad = lane >> 4;
  int l16  = lane & 15;
  int rb = blockIdx.x * 64 + wave * 16;

  fvec4 acc[8];
  #pragma unroll
  for (int t = 0; t < 8; t++)
    #pragma unroll
    for (int i = 0; i < 4; i++) acc[t][i] = 0.f;

  int arow = rb + l16; if (arow >= N_NODES) arow = N_NODES - 1;
  const ushort* aggb = agg + (size_t)arow * HD + quad * 8;
  const ushort* hb   = h   + (size_t)arow * HD + quad * 8;

  #pragma unroll
  for (int k0 = 0; k0 < 256; k0 += 32){
    const ushort* ab = (k0 < 128) ? (aggb + k0) : (hb + (k0 - 128));
    bvec8 a = *(const bvec8*)ab;
    #pragma unroll
    for (int t = 0; t < 8; t++){
      bvec8 b = *(const bvec8*)(Wc + (t * 16 + l16) * 256 + k0 + quad * 8);
      acc[t] = __builtin_amdgcn_mfma_f32_16x16x32_bf16(a, b, acc[t], 0, 0, 0);
    }
  }

  if (MODE == 1){
    const float* bias  = vecs + 640;
    const float* gammav = vecs + 768;
    const float* betav  = vecs + 896;
    float zv[8][4];
    float s1[4] = {0.f, 0.f, 0.f, 0.f};
    float s2[4] = {0.f, 0.f, 0.f, 0.f};
    #pragma unroll
    for (int t = 0; t < 8; t++){
      float bc = bias[t * 16 + l16];
      #pragma unroll
      for (int i = 0; i < 4; i++){
        float v = acc[t][i] + bc;
        zv[t][i] = v;
        s1[i] += v;
        s2[i] += v * v;
      }
    }
    #pragma unroll
    for (int m = 1; m < 16; m <<= 1){
      #pragma unroll
      for (int i = 0; i < 4; i++){
        s1[i] += __shfl_xor(s1[i], m, 64);
        s2[i] += __shfl_xor(s2[i], m, 64);
      }
    }
    float mu[4], rs[4];
    #pragma unroll
    for (int i = 0; i < 4; i++){
      mu[i] = s1[i] * (1.f / 128.f);
      float var = s2[i] * (1.f / 128.f) - mu[i] * mu[i];
      rs[i] = rsqrtf(var + LN_EPS);
    }
    ushort* ob = (ushort*)outp;
    #pragma unroll
    for (int t = 0; t < 8; t++){
      int col = t * 16 + l16;
      float g = gammav[col], bt = betav[col];
      #pragma unroll
      for (int i = 0; i < 4; i++){
        int row = rb + quad * 4 + i;
        if (row >= N_NODES) continue;
        float v = (zv[t][i] - mu[i]) * rs[i] * g + bt;
        v = fmaxf(v, 0.f);
        ob[(size_t)row * HD + col] = f2bf(v);
      }
    }
  } else {
    const float* bias = vecs + 1024;
    #pragma unroll
    for (int t = 0; t < 8; t++){
      int col = t * 16 + l16;
      float bc = bias[col];
      #pragma unroll
      for (int i = 0; i < 4; i++){
        int row = rb + quad * 4 + i;
        if (row >= N_NODES) continue;
        float v = acc[t][i] + bc;
        if (f32) ((float*)outp)[(size_t)row * HD + col] = v;
        else     ((ushort*)outp)[(size_t)row * HD + col] = f2bf(v);
      }
    }
  }
}

extern "C" void kernel_launch(void* const* d_in, const int* in_sizes, int n_in,
                              void* d_out, int out_size, void* d_ws, size_t ws_size,
                              hipStream_t stream) {
  const void* x          = d_in[0];
  const int*  ei         = (const int*)d_in[1];
  const int*  node_kind  = (const int*)d_in[2];
  const void* W_in       = d_in[3];
  const void* b_in       = d_in[4];
  const void* kind_embed = d_in[5];
  const void* ext_seed   = d_in[6];
  const void* Wl1        = d_in[7];
  const void* bl1        = d_in[8];
  const void* Wr1        = d_in[9];
  const void* gammap     = d_in[10];
  const void* betap      = d_in[11];
  const void* Wl2        = d_in[12];
  const void* bl2        = d_in[13];
  const void* Wr2        = d_in[14];
  const int* src = ei;
  const int* dst = ei + N_EDGES;

  char* ws = (char*)d_ws;
  size_t off = 0;
  auto alloc = [&](size_t bytes) -> void* {
    void* p = ws + off;
    off += (bytes + 255) & ~(size_t)255;
    return p;
  };
  int*    flag     = (int*)alloc(256);
  int*    cnt      = (int*)alloc(N_NODES * 4);
  int*    cursor   = (int*)alloc(N_NODES * 4);
  int*    rowstart = (int*)alloc((N_NODES + 1) * 4);
  int*    esrc     = (int*)alloc(N_EDGES * 4);
  ushort* WtA      = (ushort*)alloc(128 * 256 * 2);
  ushort* Wc1      = (ushort*)alloc(128 * 256 * 2);
  ushort* Wc2      = (ushort*)alloc(128 * 256 * 2);
  float*  vecs     = (float*)alloc(1152 * 4);
  ushort* h0       = (ushort*)alloc((size_t)N_NODES * HD * 2);
  ushort* h1       = (ushort*)alloc((size_t)N_NODES * HD * 2);
  ushort* aggb     = (ushort*)alloc((size_t)N_NODES * HD * 2);

  k_probe<<<1, 256, 0, stream>>>((const ushort*)x, flag);
  k_zero<<<(N_NODES + 255) / 256, 256, 0, stream>>>(cnt, cursor);
  k_prep_w<<<(128 * 256 + 255) / 256, 256, 0, stream>>>(flag, W_in, Wl1, Wr1, Wl2, Wr2, WtA, Wc1, Wc2);
  k_prep_vec<<<1, 256, 0, stream>>>(flag, b_in, kind_embed, ext_seed, bl1, gammap, betap, bl2, vecs);
  k_count<<<(N_EDGES + 255) / 256, 256, 0, stream>>>(dst, cnt);
  k_scan<<<1, 1024, 0, stream>>>(cnt, rowstart);
  k_fill<<<(N_EDGES + 255) / 256, 256, 0, stream>>>(src, dst, rowstart, cursor, esrc);

  int gemm_grid = (N_NODES + 63) / 64;
  k_gemm_in<<<gemm_grid, 256, 0, stream>>>(flag, x, WtA, vecs, node_kind, h0);
  k_gather<<<(N_NODES + 3) / 4, 256, 0, stream>>>(h0, rowstart, esrc, aggb);
  k_conv<1><<<gemm_grid, 256, 0, stream>>>(flag, aggb, h0, Wc1, vecs, (void*)h1);
  k_gather<<<(N_NODES + 3) / 4, 256, 0, stream>>>(h1, rowstart, esrc, aggb);
  k_conv<2><<<gemm_grid, 256, 0, stream>>>(flag, aggb, h1, Wc2, vecs, d_out);
}

// Round 3
// 434.178 us; speedup vs baseline: 1.1398x; 1.1398x over previous
//
#include <hip/hip_runtime.h>
#include <stdint.h>

#define N_NODES 50000
#define N_EDGES 625000
#define DIN 256
#define HD 128
#define LN_EPS 1e-5f

typedef __attribute__((ext_vector_type(8))) short bvec8;
typedef __attribute__((ext_vector_type(4))) float fvec4;

__device__ inline float bf2f(ushort u){
  union { uint32_t u32; float f; } c; c.u32 = ((uint32_t)u) << 16; return c.f;
}
__device__ inline ushort f2bf(float f){
  union { float f; uint32_t u; } c; c.f = f;
  uint32_t u = c.u;
  return (ushort)((u + 0x7fffu + ((u >> 16) & 1u)) >> 16);
}
__device__ inline float rdany(const void* p, int i, int f32){
  return f32 ? ((const float*)p)[i] : bf2f(((const ushort*)p)[i]);
}

// ---------------- dtype probe ----------------
__global__ void k_probe(const ushort* __restrict__ x, int* __restrict__ flag){
  __shared__ int red[256];
  int t = threadIdx.x;
  int c = 0;
  for (int j = 0; j < 8; j++){
    ushort u = x[t * 8 + j];
    int e = (u >> 7) & 0xff;
    if (e >= 0x88 || (e != 0 && e <= 0x70)) c++;
  }
  red[t] = c;
  __syncthreads();
  for (int off = 128; off > 0; off >>= 1){
    if (t < off) red[t] += red[t + off];
    __syncthreads();
  }
  if (t == 0) flag[0] = (red[0] > 100) ? 1 : 0;
}

// ---------------- CSR build ----------------
__global__ void k_zero(int* cnt, int* cursor, int* total){
  int i = blockIdx.x * 256 + threadIdx.x;
  if (i < N_NODES){ cnt[i] = 0; cursor[i] = 0; }
  if (i == 0) total[0] = 0;
}

__global__ void k_count(const int* __restrict__ dst, int* __restrict__ cnt){
  int e = blockIdx.x * 256 + threadIdx.x;
  if (e < N_EDGES) atomicAdd(&cnt[dst[e]], 1);
}

// unordered segment allocator: wave-level inclusive scan + 1 atomic per wave.
// Segment ORDER is irrelevant for mean-aggregation; only disjointness matters.
__global__ void k_assign(const int* __restrict__ cnt, int* __restrict__ rowstart,
                         int* __restrict__ total){
  int i = blockIdx.x * 256 + threadIdx.x;
  int lane = threadIdx.x & 63;
  int c = (i < N_NODES) ? cnt[i] : 0;
  int scan = c;
  #pragma unroll
  for (int m = 1; m < 64; m <<= 1){
    int v = __shfl_up(scan, m, 64);
    if (lane >= m) scan += v;
  }
  int wave_total = __shfl(scan, 63, 64);
  int base = 0;
  if (lane == 63) base = atomicAdd(total, wave_total);
  base = __shfl(base, 63, 64);
  if (i < N_NODES) rowstart[i] = base + scan - c;
}

__global__ void k_fill(const int* __restrict__ src, const int* __restrict__ dst,
                       const int* __restrict__ rowstart, int* __restrict__ cursor,
                       int* __restrict__ esrc){
  int e = blockIdx.x * 256 + threadIdx.x;
  if (e < N_EDGES){
    int d = dst[e];
    int pos = atomicAdd(&cursor[d], 1);
    esrc[rowstart[d] + pos] = src[e];
  }
}

// ---------------- weight prep (dtype-adaptive) ----------------
__global__ void k_prep_w(const int* __restrict__ flag,
                         const void* __restrict__ W_in,
                         const void* __restrict__ Wl1, const void* __restrict__ Wr1,
                         const void* __restrict__ Wl2, const void* __restrict__ Wr2,
                         ushort* __restrict__ WtA, ushort* __restrict__ Wc1, ushort* __restrict__ Wc2){
  int f32 = flag[0];
  int idx = blockIdx.x * 256 + threadIdx.x;
  if (idx >= 128 * 256) return;
  int n = idx >> 8;
  int k = idx & 255;
  WtA[n * 256 + k] = f2bf(rdany(W_in, k * 128 + n, f32));
  if (k < 128){
    Wc1[n * 256 + k] = f2bf(rdany(Wl1, k * 128 + n, f32));
    Wc2[n * 256 + k] = f2bf(rdany(Wl2, k * 128 + n, f32));
  } else {
    Wc1[n * 256 + k] = f2bf(rdany(Wr1, (k - 128) * 128 + n, f32));
    Wc2[n * 256 + k] = f2bf(rdany(Wr2, (k - 128) * 128 + n, f32));
  }
}

// small vectors -> fp32 staging
__global__ void k_prep_vec(const int* __restrict__ flag,
                           const void* b_in, const void* kind_embed, const void* ext_seed,
                           const void* bl1, const void* gammap, const void* betap,
                           const void* bl2, float* __restrict__ vecs){
  int f32 = flag[0];
  for (int i = threadIdx.x; i < 1152; i += 256){
    float v;
    if (i < 128)       v = rdany(b_in, i, f32);
    else if (i < 512)  v = rdany(kind_embed, i - 128, f32);
    else if (i < 640)  v = rdany(ext_seed, i - 512, f32);
    else if (i < 768)  v = rdany(bl1, i - 640, f32);
    else if (i < 896)  v = rdany(gammap, i - 768, f32);
    else if (i < 1024) v = rdany(betap, i - 896, f32);
    else               v = rdany(bl2, i - 1024, f32);
    vecs[i] = v;
  }
}

// ---------------- input GEMM ----------------
__global__ void __launch_bounds__(256) k_gemm_in(
    const int* __restrict__ flag, const void* __restrict__ xin,
    const ushort* __restrict__ WtA, const float* __restrict__ vecs,
    const int* __restrict__ node_kind, ushort* __restrict__ h0){
  int f32 = flag[0];
  int wave = threadIdx.x >> 6;
  int lane = threadIdx.x & 63;
  int quad = lane >> 4;
  int l16  = lane & 15;
  int rb = blockIdx.x * 64 + wave * 16;

  fvec4 acc[8];
  #pragma unroll
  for (int t = 0; t < 8; t++)
    #pragma unroll
    for (int i = 0; i < 4; i++) acc[t][i] = 0.f;

  int arow = rb + l16; if (arow >= N_NODES) arow = N_NODES - 1;
  const ushort* abf = (const ushort*)xin + (size_t)arow * DIN + quad * 8;
  const float*  af  = (const float*)xin + (size_t)arow * DIN + quad * 8;

  #pragma unroll
  for (int k0 = 0; k0 < DIN; k0 += 32){
    bvec8 a;
    if (f32){
      fvec4 lo = *(const fvec4*)(af + k0);
      fvec4 hi = *(const fvec4*)(af + k0 + 4);
      a[0] = (short)f2bf(lo[0]); a[1] = (short)f2bf(lo[1]);
      a[2] = (short)f2bf(lo[2]); a[3] = (short)f2bf(lo[3]);
      a[4] = (short)f2bf(hi[0]); a[5] = (short)f2bf(hi[1]);
      a[6] = (short)f2bf(hi[2]); a[7] = (short)f2bf(hi[3]);
    } else {
      a = *(const bvec8*)(abf + k0);
    }
    #pragma unroll
    for (int t = 0; t < 8; t++){
      bvec8 b = *(const bvec8*)(WtA + (t * 16 + l16) * DIN + k0 + quad * 8);
      acc[t] = __builtin_amdgcn_mfma_f32_16x16x32_bf16(a, b, acc[t], 0, 0, 0);
    }
  }

  const float* b_in  = vecs;
  const float* kinde = vecs + 128;
  const float* ext   = vecs + 512;
  #pragma unroll
  for (int i = 0; i < 4; i++){
    int row = rb + quad * 4 + i;
    if (row >= N_NODES) continue;
    int kind = node_kind[row];
    float extf = (kind != 0) ? 1.f : 0.f;
    #pragma unroll
    for (int t = 0; t < 8; t++){
      int col = t * 16 + l16;
      float v = acc[t][i] + b_in[col] + kinde[kind * HD + col] + extf * ext[col];
      h0[(size_t)row * HD + col] = f2bf(v);
    }
  }
}

// ---------------- mean aggregation (CSR walk) ----------------
__global__ void __launch_bounds__(256) k_gather(
    const ushort* __restrict__ h, const int* __restrict__ rowstart,
    const int* __restrict__ cnt, const int* __restrict__ esrc,
    ushort* __restrict__ agg){
  int n = blockIdx.x * 4 + (threadIdx.x >> 6);
  int lane = threadIdx.x & 63;
  if (n >= N_NODES) return;
  int b = rowstart[n];
  int deg = cnt[n];
  int e = b + deg;
  float a0 = 0.f, a1 = 0.f;
  for (int i = b; i < e; i++){
    int s = esrc[i];
    uint32_t pv = *(const uint32_t*)(h + (size_t)s * HD + lane * 2);
    a0 += bf2f((ushort)(pv & 0xffffu));
    a1 += bf2f((ushort)(pv >> 16));
  }
  float scale = (deg > 0) ? 1.f / (float)deg : 0.f;
  a0 *= scale; a1 *= scale;
  uint32_t ov = (uint32_t)f2bf(a0) | ((uint32_t)f2bf(a1) << 16);
  *(uint32_t*)(agg + (size_t)n * HD + lane * 2) = ov;
}

// ---------------- conv GEMM ----------------
template<int MODE>
__global__ void __launch_bounds__(256) k_conv(
    const int* __restrict__ flag,
    const ushort* __restrict__ agg, const ushort* __restrict__ h,
    const ushort* __restrict__ Wc, const float* __restrict__ vecs,
    void* __restrict__ outp){
  int f32 = flag[0];
  int wave = threadIdx.x >> 6;
  int lane = threadIdx.x & 63;
  int quad = lane >> 4;
  int l16  = lane & 15;
  int rb = blockIdx.x * 64 + wave * 16;

  fvec4 acc[8];
  #pragma unroll
  for (int t = 0; t < 8; t++)
    #pragma unroll
    for (int i = 0; i < 4; i++) acc[t][i] = 0.f;

  int arow = rb + l16; if (arow >= N_NODES) arow = N_NODES - 1;
  const ushort* aggb = agg + (size_t)arow * HD + quad * 8;
  const ushort* hb   = h   + (size_t)arow * HD + quad * 8;

  #pragma unroll
  for (int k0 = 0; k0 < 256; k0 += 32){
    const ushort* ab = (k0 < 128) ? (aggb + k0) : (hb + (k0 - 128));
    bvec8 a = *(const bvec8*)ab;
    #pragma unroll
    for (int t = 0; t < 8; t++){
      bvec8 b = *(const bvec8*)(Wc + (t * 16 + l16) * 256 + k0 + quad * 8);
      acc[t] = __builtin_amdgcn_mfma_f32_16x16x32_bf16(a, b, acc[t], 0, 0, 0);
    }
  }

  if (MODE == 1){
    const float* bias   = vecs + 640;
    const float* gammav = vecs + 768;
    const float* betav  = vecs + 896;
    float zv[8][4];
    float s1[4] = {0.f, 0.f, 0.f, 0.f};
    float s2[4] = {0.f, 0.f, 0.f, 0.f};
    #pragma unroll
    for (int t = 0; t < 8; t++){
      float bc = bias[t * 16 + l16];
      #pragma unroll
      for (int i = 0; i < 4; i++){
        float v = acc[t][i] + bc;
        zv[t][i] = v;
        s1[i] += v;
        s2[i] += v * v;
      }
    }
    #pragma unroll
    for (int m = 1; m < 16; m <<= 1){
      #pragma unroll
      for (int i = 0; i < 4; i++){
        s1[i] += __shfl_xor(s1[i], m, 64);
        s2[i] += __shfl_xor(s2[i], m, 64);
      }
    }
    float mu[4], rs[4];
    #pragma unroll
    for (int i = 0; i < 4; i++){
      mu[i] = s1[i] * (1.f / 128.f);
      float var = s2[i] * (1.f / 128.f) - mu[i] * mu[i];
      rs[i] = rsqrtf(var + LN_EPS);
    }
    ushort* ob = (ushort*)outp;
    #pragma unroll
    for (int t = 0; t < 8; t++){
      int col = t * 16 + l16;
      float g = gammav[col], bt = betav[col];
      #pragma unroll
      for (int i = 0; i < 4; i++){
        int row = rb + quad * 4 + i;
        if (row >= N_NODES) continue;
        float v = (zv[t][i] - mu[i]) * rs[i] * g + bt;
        v = fmaxf(v, 0.f);
        ob[(size_t)row * HD + col] = f2bf(v);
      }
    }
  } else {
    const float* bias = vecs + 1024;
    #pragma unroll
    for (int t = 0; t < 8; t++){
      int col = t * 16 + l16;
      float bc = bias[col];
      #pragma unroll
      for (int i = 0; i < 4; i++){
        int row = rb + quad * 4 + i;
        if (row >= N_NODES) continue;
        float v = acc[t][i] + bc;
        if (f32) ((float*)outp)[(size_t)row * HD + col] = v;
        else     ((ushort*)outp)[(size_t)row * HD + col] = f2bf(v);
      }
    }
  }
}

extern "C" void kernel_launch(void* const* d_in, const int* in_sizes, int n_in,
                              void* d_out, int out_size, void* d_ws, size_t ws_size,
                              hipStream_t stream) {
  const void* x          = d_in[0];
  const int*  ei         = (const int*)d_in[1];
  const int*  node_kind  = (const int*)d_in[2];
  const void* W_in       = d_in[3];
  const void* b_in       = d_in[4];
  const void* kind_embed = d_in[5];
  const void* ext_seed   = d_in[6];
  const void* Wl1        = d_in[7];
  const void* bl1        = d_in[8];
  const void* Wr1        = d_in[9];
  const void* gammap     = d_in[10];
  const void* betap      = d_in[11];
  const void* Wl2        = d_in[12];
  const void* bl2        = d_in[13];
  const void* Wr2        = d_in[14];
  const int* src = ei;
  const int* dst = ei + N_EDGES;

  char* ws = (char*)d_ws;
  size_t off = 0;
  auto alloc = [&](size_t bytes) -> void* {
    void* p = ws + off;
    off += (bytes + 255) & ~(size_t)255;
    return p;
  };
  int*    flag     = (int*)alloc(256);
  int*    total    = (int*)alloc(256);
  int*    cnt      = (int*)alloc(N_NODES * 4);
  int*    cursor   = (int*)alloc(N_NODES * 4);
  int*    rowstart = (int*)alloc(N_NODES * 4);
  int*    esrc     = (int*)alloc(N_EDGES * 4);
  ushort* WtA      = (ushort*)alloc(128 * 256 * 2);
  ushort* Wc1      = (ushort*)alloc(128 * 256 * 2);
  ushort* Wc2      = (ushort*)alloc(128 * 256 * 2);
  float*  vecs     = (float*)alloc(1152 * 4);
  ushort* h0       = (ushort*)alloc((size_t)N_NODES * HD * 2);
  ushort* h1       = (ushort*)alloc((size_t)N_NODES * HD * 2);
  ushort* aggb     = (ushort*)alloc((size_t)N_NODES * HD * 2);

  k_probe<<<1, 256, 0, stream>>>((const ushort*)x, flag);
  k_zero<<<(N_NODES + 255) / 256, 256, 0, stream>>>(cnt, cursor, total);
  k_prep_w<<<(128 * 256 + 255) / 256, 256, 0, stream>>>(flag, W_in, Wl1, Wr1, Wl2, Wr2, WtA, Wc1, Wc2);
  k_prep_vec<<<1, 256, 0, stream>>>(flag, b_in, kind_embed, ext_seed, bl1, gammap, betap, bl2, vecs);
  k_count<<<(N_EDGES + 255) / 256, 256, 0, stream>>>(dst, cnt);
  k_assign<<<(N_NODES + 255) / 256, 256, 0, stream>>>(cnt, rowstart, total);
  k_fill<<<(N_EDGES + 255) / 256, 256, 0, stream>>>(src, dst, rowstart, cursor, esrc);

  int gemm_grid = (N_NODES + 63) / 64;
  k_gemm_in<<<gemm_grid, 256, 0, stream>>>(flag, x, WtA, vecs, node_kind, h0);
  k_gather<<<(N_NODES + 3) / 4, 256, 0, stream>>>(h0, rowstart, cnt, esrc, aggb);
  k_conv<1><<<gemm_grid, 256, 0, stream>>>(flag, aggb, h0, Wc1, vecs, (void*)h1);
  k_gather<<<(N_NODES + 3) / 4, 256, 0, stream>>>(h1, rowstart, cnt, esrc, aggb);
  k_conv<2><<<gemm_grid, 256, 0, stream>>>(flag, aggb, h1, Wc2, vecs, d_out);
}

// Round 4
// 365.567 us; speedup vs baseline: 1.3538x; 1.1877x over previous
//
#include <hip/hip_runtime.h>
#include <stdint.h>

#define N_NODES 50000
#define N_EDGES 625000
#define DIN 256
#define HD 128
#define LN_EPS 1e-5f

typedef __attribute__((ext_vector_type(8))) short bvec8;
typedef __attribute__((ext_vector_type(4))) float fvec4;

__device__ inline float bf2f(ushort u){
  union { uint32_t u32; float f; } c; c.u32 = ((uint32_t)u) << 16; return c.f;
}
__device__ inline ushort f2bf(float f){
  union { float f; uint32_t u; } c; c.f = f;
  uint32_t u = c.u;
  return (ushort)((u + 0x7fffu + ((u >> 16) & 1u)) >> 16);
}
__device__ inline float rdany(const void* p, int i, int f32){
  return f32 ? ((const float*)p)[i] : bf2f(((const ushort*)p)[i]);
}

// ---------------- dtype probe ----------------
__global__ void k_probe(const ushort* __restrict__ x, int* __restrict__ flag){
  __shared__ int red[256];
  int t = threadIdx.x;
  int c = 0;
  for (int j = 0; j < 8; j++){
    ushort u = x[t * 8 + j];
    int e = (u >> 7) & 0xff;
    if (e >= 0x88 || (e != 0 && e <= 0x70)) c++;
  }
  red[t] = c;
  __syncthreads();
  for (int off = 128; off > 0; off >>= 1){
    if (t < off) red[t] += red[t + off];
    __syncthreads();
  }
  if (t == 0) flag[0] = (red[0] > 100) ? 1 : 0;
}

// ---------------- CSR build ----------------
__global__ void k_zero(int* cnt, int* cursor, int* total){
  int i = blockIdx.x * 256 + threadIdx.x;
  if (i < N_NODES){ cnt[i] = 0; cursor[i] = 0; }
  if (i == 0) total[0] = 0;
}

__global__ void k_count(const int* __restrict__ dst, int* __restrict__ cnt){
  int e = blockIdx.x * 256 + threadIdx.x;
  if (e < N_EDGES) atomicAdd(&cnt[dst[e]], 1);
}

// unordered segment allocator: wave scan + 1 atomic per wave (order irrelevant for mean-agg)
__global__ void k_assign(const int* __restrict__ cnt, int* __restrict__ rowstart,
                         int* __restrict__ total){
  int i = blockIdx.x * 256 + threadIdx.x;
  int lane = threadIdx.x & 63;
  int c = (i < N_NODES) ? cnt[i] : 0;
  int scan = c;
  #pragma unroll
  for (int m = 1; m < 64; m <<= 1){
    int v = __shfl_up(scan, m, 64);
    if (lane >= m) scan += v;
  }
  int wave_total = __shfl(scan, 63, 64);
  int base = 0;
  if (lane == 63) base = atomicAdd(total, wave_total);
  base = __shfl(base, 63, 64);
  if (i < N_NODES) rowstart[i] = base + scan - c;
}

__global__ void k_fill(const int* __restrict__ src, const int* __restrict__ dst,
                       const int* __restrict__ rowstart, int* __restrict__ cursor,
                       int* __restrict__ esrc){
  int e = blockIdx.x * 256 + threadIdx.x;
  if (e < N_EDGES){
    int d = dst[e];
    int pos = atomicAdd(&cursor[d], 1);
    esrc[rowstart[d] + pos] = src[e];
  }
}

// ---------------- weight prep (dtype-adaptive) ----------------
__global__ void k_prep_w(const int* __restrict__ flag,
                         const void* __restrict__ W_in,
                         const void* __restrict__ Wl1, const void* __restrict__ Wr1,
                         const void* __restrict__ Wl2, const void* __restrict__ Wr2,
                         ushort* __restrict__ WtA, ushort* __restrict__ Wc1, ushort* __restrict__ Wc2){
  int f32 = flag[0];
  int idx = blockIdx.x * 256 + threadIdx.x;
  if (idx >= 128 * 256) return;
  int n = idx >> 8;
  int k = idx & 255;
  WtA[n * 256 + k] = f2bf(rdany(W_in, k * 128 + n, f32));
  if (k < 128){
    Wc1[n * 256 + k] = f2bf(rdany(Wl1, k * 128 + n, f32));
    Wc2[n * 256 + k] = f2bf(rdany(Wl2, k * 128 + n, f32));
  } else {
    Wc1[n * 256 + k] = f2bf(rdany(Wr1, (k - 128) * 128 + n, f32));
    Wc2[n * 256 + k] = f2bf(rdany(Wr2, (k - 128) * 128 + n, f32));
  }
}

// small vectors -> fp32 staging
__global__ void k_prep_vec(const int* __restrict__ flag,
                           const void* b_in, const void* kind_embed, const void* ext_seed,
                           const void* bl1, const void* gammap, const void* betap,
                           const void* bl2, float* __restrict__ vecs){
  int f32 = flag[0];
  for (int i = threadIdx.x; i < 1152; i += 256){
    float v;
    if (i < 128)       v = rdany(b_in, i, f32);
    else if (i < 512)  v = rdany(kind_embed, i - 128, f32);
    else if (i < 640)  v = rdany(ext_seed, i - 512, f32);
    else if (i < 768)  v = rdany(bl1, i - 640, f32);
    else if (i < 896)  v = rdany(gammap, i - 768, f32);
    else if (i < 1024) v = rdany(betap, i - 896, f32);
    else               v = rdany(bl2, i - 1024, f32);
    vecs[i] = v;
  }
}

// ---------------- input GEMM ----------------
__global__ void __launch_bounds__(256) k_gemm_in(
    const int* __restrict__ flag, const void* __restrict__ xin,
    const ushort* __restrict__ WtA, const float* __restrict__ vecs,
    const int* __restrict__ node_kind, ushort* __restrict__ h0){
  int f32 = flag[0];
  int wave = threadIdx.x >> 6;
  int lane = threadIdx.x & 63;
  int quad = lane >> 4;
  int l16  = lane & 15;
  int rb = blockIdx.x * 64 + wave * 16;

  fvec4 acc[8];
  #pragma unroll
  for (int t = 0; t < 8; t++)
    #pragma unroll
    for (int i = 0; i < 4; i++) acc[t][i] = 0.f;

  int arow = rb + l16; if (arow >= N_NODES) arow = N_NODES - 1;
  const ushort* abf = (const ushort*)xin + (size_t)arow * DIN + quad * 8;
  const float*  af  = (const float*)xin + (size_t)arow * DIN + quad * 8;

  #pragma unroll
  for (int k0 = 0; k0 < DIN; k0 += 32){
    bvec8 a;
    if (f32){
      fvec4 lo = *(const fvec4*)(af + k0);
      fvec4 hi = *(const fvec4*)(af + k0 + 4);
      a[0] = (short)f2bf(lo[0]); a[1] = (short)f2bf(lo[1]);
      a[2] = (short)f2bf(lo[2]); a[3] = (short)f2bf(lo[3]);
      a[4] = (short)f2bf(hi[0]); a[5] = (short)f2bf(hi[1]);
      a[6] = (short)f2bf(hi[2]); a[7] = (short)f2bf(hi[3]);
    } else {
      a = *(const bvec8*)(abf + k0);
    }
    #pragma unroll
    for (int t = 0; t < 8; t++){
      bvec8 b = *(const bvec8*)(WtA + (t * 16 + l16) * DIN + k0 + quad * 8);
      acc[t] = __builtin_amdgcn_mfma_f32_16x16x32_bf16(a, b, acc[t], 0, 0, 0);
    }
  }

  const float* b_in  = vecs;
  const float* kinde = vecs + 128;
  const float* ext   = vecs + 512;
  #pragma unroll
  for (int i = 0; i < 4; i++){
    int row = rb + quad * 4 + i;
    if (row >= N_NODES) continue;
    int kind = node_kind[row];
    float extf = (kind != 0) ? 1.f : 0.f;
    #pragma unroll
    for (int t = 0; t < 8; t++){
      int col = t * 16 + l16;
      float v = acc[t][i] + b_in[col] + kinde[kind * HD + col] + extf * ext[col];
      h0[(size_t)row * HD + col] = f2bf(v);
    }
  }
}

// ---------------- mean aggregation: 4 edge-groups x 16 lanes, 8 rows in flight ----------------
__device__ inline void acc_row(float* acc, uint4 p){
  const uint32_t* pw = (const uint32_t*)&p;
  #pragma unroll
  for (int j = 0; j < 4; j++){
    uint32_t u = pw[j];
    acc[2 * j]     += bf2f((ushort)(u & 0xffffu));
    acc[2 * j + 1] += bf2f((ushort)(u >> 16));
  }
}

__global__ void __launch_bounds__(256) k_gather(
    const ushort* __restrict__ h, const int* __restrict__ rowstart,
    const int* __restrict__ cnt, const int* __restrict__ esrc,
    ushort* __restrict__ agg){
  int n = blockIdx.x * 4 + (threadIdx.x >> 6);
  int lane = threadIdx.x & 63;
  int eg  = lane >> 4;   // edge group 0..3
  int l16 = lane & 15;   // column group: cols l16*8 .. l16*8+7
  if (n >= N_NODES) return;
  int b = rowstart[n];
  int deg = cnt[n];
  int e = b + deg;

  float acc[8];
  #pragma unroll
  for (int j = 0; j < 8; j++) acc[j] = 0.f;

  for (int i = b; i < e; i += 8){
    int iA = i + eg;
    int iB = i + 4 + eg;
    bool vA = iA < e;
    bool vB = iB < e;
    int last = e - 1;
    int sA = esrc[vA ? iA : last];
    int sB = esrc[vB ? iB : last];
    uint4 pA = {0, 0, 0, 0}, pB = {0, 0, 0, 0};
    if (vA) pA = *(const uint4*)(h + (size_t)sA * HD + l16 * 8);
    if (vB) pB = *(const uint4*)(h + (size_t)sB * HD + l16 * 8);
    acc_row(acc, pA);
    acc_row(acc, pB);
  }

  // reduce across the 4 edge groups (lanes differing in bits 4,5)
  #pragma unroll
  for (int j = 0; j < 8; j++){
    acc[j] += __shfl_xor(acc[j], 16, 64);
    acc[j] += __shfl_xor(acc[j], 32, 64);
  }

  if (eg == 0){
    float scale = (deg > 0) ? 1.f / (float)deg : 0.f;
    uint4 ov;
    uint32_t* ow = (uint32_t*)&ov;
    #pragma unroll
    for (int j = 0; j < 4; j++){
      ow[j] = (uint32_t)f2bf(acc[2 * j] * scale) |
              ((uint32_t)f2bf(acc[2 * j + 1] * scale) << 16);
    }
    *(uint4*)(agg + (size_t)n * HD + l16 * 8) = ov;
  }
}

// ---------------- conv GEMM ----------------
template<int MODE>
__global__ void __launch_bounds__(256) k_conv(
    const int* __restrict__ flag,
    const ushort* __restrict__ agg, const ushort* __restrict__ h,
    const ushort* __restrict__ Wc, const float* __restrict__ vecs,
    void* __restrict__ outp){
  int f32 = flag[0];
  int wave = threadIdx.x >> 6;
  int lane = threadIdx.x & 63;
  int quad = lane >> 4;
  int l16  = lane & 15;
  int rb = blockIdx.x * 64 + wave * 16;

  fvec4 acc[8];
  #pragma unroll
  for (int t = 0; t < 8; t++)
    #pragma unroll
    for (int i = 0; i < 4; i++) acc[t][i] = 0.f;

  int arow = rb + l16; if (arow >= N_NODES) arow = N_NODES - 1;
  const ushort* aggb = agg + (size_t)arow * HD + quad * 8;
  const ushort* hb   = h   + (size_t)arow * HD + quad * 8;

  #pragma unroll
  for (int k0 = 0; k0 < 256; k0 += 32){
    const ushort* ab = (k0 < 128) ? (aggb + k0) : (hb + (k0 - 128));
    bvec8 a = *(const bvec8*)ab;
    #pragma unroll
    for (int t = 0; t < 8; t++){
      bvec8 b = *(const bvec8*)(Wc + (t * 16 + l16) * 256 + k0 + quad * 8);
      acc[t] = __builtin_amdgcn_mfma_f32_16x16x32_bf16(a, b, acc[t], 0, 0, 0);
    }
  }

  if (MODE == 1){
    const float* bias   = vecs + 640;
    const float* gammav = vecs + 768;
    const float* betav  = vecs + 896;
    float zv[8][4];
    float s1[4] = {0.f, 0.f, 0.f, 0.f};
    float s2[4] = {0.f, 0.f, 0.f, 0.f};
    #pragma unroll
    for (int t = 0; t < 8; t++){
      float bc = bias[t * 16 + l16];
      #pragma unroll
      for (int i = 0; i < 4; i++){
        float v = acc[t][i] + bc;
        zv[t][i] = v;
        s1[i] += v;
        s2[i] += v * v;
      }
    }
    #pragma unroll
    for (int m = 1; m < 16; m <<= 1){
      #pragma unroll
      for (int i = 0; i < 4; i++){
        s1[i] += __shfl_xor(s1[i], m, 64);
        s2[i] += __shfl_xor(s2[i], m, 64);
      }
    }
    float mu[4], rs[4];
    #pragma unroll
    for (int i = 0; i < 4; i++){
      mu[i] = s1[i] * (1.f / 128.f);
      float var = s2[i] * (1.f / 128.f) - mu[i] * mu[i];
      rs[i] = rsqrtf(var + LN_EPS);
    }
    ushort* ob = (ushort*)outp;
    #pragma unroll
    for (int t = 0; t < 8; t++){
      int col = t * 16 + l16;
      float g = gammav[col], bt = betav[col];
      #pragma unroll
      for (int i = 0; i < 4; i++){
        int row = rb + quad * 4 + i;
        if (row >= N_NODES) continue;
        float v = (zv[t][i] - mu[i]) * rs[i] * g + bt;
        v = fmaxf(v, 0.f);
        ob[(size_t)row * HD + col] = f2bf(v);
      }
    }
  } else {
    const float* bias = vecs + 1024;
    #pragma unroll
    for (int t = 0; t < 8; t++){
      int col = t * 16 + l16;
      float bc = bias[col];
      #pragma unroll
      for (int i = 0; i < 4; i++){
        int row = rb + quad * 4 + i;
        if (row >= N_NODES) continue;
        float v = acc[t][i] + bc;
        if (f32) ((float*)outp)[(size_t)row * HD + col] = v;
        else     ((ushort*)outp)[(size_t)row * HD + col] = f2bf(v);
      }
    }
  }
}

extern "C" void kernel_launch(void* const* d_in, const int* in_sizes, int n_in,
                              void* d_out, int out_size, void* d_ws, size_t ws_size,
                              hipStream_t stream) {
  const void* x          = d_in[0];
  const int*  ei         = (const int*)d_in[1];
  const int*  node_kind  = (const int*)d_in[2];
  const void* W_in       = d_in[3];
  const void* b_in       = d_in[4];
  const void* kind_embed = d_in[5];
  const void* ext_seed   = d_in[6];
  const void* Wl1        = d_in[7];
  const void* bl1        = d_in[8];
  const void* Wr1        = d_in[9];
  const void* gammap     = d_in[10];
  const void* betap      = d_in[11];
  const void* Wl2        = d_in[12];
  const void* bl2        = d_in[13];
  const void* Wr2        = d_in[14];
  const int* src = ei;
  const int* dst = ei + N_EDGES;

  char* ws = (char*)d_ws;
  size_t off = 0;
  auto alloc = [&](size_t bytes) -> void* {
    void* p = ws + off;
    off += (bytes + 255) & ~(size_t)255;
    return p;
  };
  int*    flag     = (int*)alloc(256);
  int*    total    = (int*)alloc(256);
  int*    cnt      = (int*)alloc(N_NODES * 4);
  int*    cursor   = (int*)alloc(N_NODES * 4);
  int*    rowstart = (int*)alloc(N_NODES * 4);
  int*    esrc     = (int*)alloc(N_EDGES * 4);
  ushort* WtA      = (ushort*)alloc(128 * 256 * 2);
  ushort* Wc1      = (ushort*)alloc(128 * 256 * 2);
  ushort* Wc2      = (ushort*)alloc(128 * 256 * 2);
  float*  vecs     = (float*)alloc(1152 * 4);
  ushort* h0       = (ushort*)alloc((size_t)N_NODES * HD * 2);
  ushort* h1       = (ushort*)alloc((size_t)N_NODES * HD * 2);
  ushort* aggb     = (ushort*)alloc((size_t)N_NODES * HD * 2);

  k_probe<<<1, 256, 0, stream>>>((const ushort*)x, flag);
  k_zero<<<(N_NODES + 255) / 256, 256, 0, stream>>>(cnt, cursor, total);
  k_prep_w<<<(128 * 256 + 255) / 256, 256, 0, stream>>>(flag, W_in, Wl1, Wr1, Wl2, Wr2, WtA, Wc1, Wc2);
  k_prep_vec<<<1, 256, 0, stream>>>(flag, b_in, kind_embed, ext_seed, bl1, gammap, betap, bl2, vecs);
  k_count<<<(N_EDGES + 255) / 256, 256, 0, stream>>>(dst, cnt);
  k_assign<<<(N_NODES + 255) / 256, 256, 0, stream>>>(cnt, rowstart, total);
  k_fill<<<(N_EDGES + 255) / 256, 256, 0, stream>>>(src, dst, rowstart, cursor, esrc);

  int gemm_grid = (N_NODES + 63) / 64;
  k_gemm_in<<<gemm_grid, 256, 0, stream>>>(flag, x, WtA, vecs, node_kind, h0);
  k_gather<<<(N_NODES + 3) / 4, 256, 0, stream>>>(h0, rowstart, cnt, esrc, aggb);
  k_conv<1><<<gemm_grid, 256, 0, stream>>>(flag, aggb, h0, Wc1, vecs, (void*)h1);
  k_gather<<<(N_NODES + 3) / 4, 256, 0, stream>>>(h1, rowstart, cnt, esrc, aggb);
  k_conv<2><<<gemm_grid, 256, 0, stream>>>(flag, aggb, h1, Wc2, vecs, d_out);
}

// Round 5
// 365.430 us; speedup vs baseline: 1.3543x; 1.0004x over previous
//
#include <hip/hip_runtime.h>
#include <stdint.h>

#define N_NODES 50000
#define N_EDGES 625000
#define DIN 256
#define HD 128
#define LN_EPS 1e-5f

typedef __attribute__((ext_vector_type(8))) short bvec8;
typedef __attribute__((ext_vector_type(4))) float fvec4;

__device__ inline float bf2f(ushort u){
  union { uint32_t u32; float f; } c; c.u32 = ((uint32_t)u) << 16; return c.f;
}
__device__ inline ushort f2bf(float f){
  union { float f; uint32_t u; } c; c.f = f;
  uint32_t u = c.u;
  return (ushort)((u + 0x7fffu + ((u >> 16) & 1u)) >> 16);
}
__device__ inline float rdany(const void* p, int i, int f32){
  return f32 ? ((const float*)p)[i] : bf2f(((const ushort*)p)[i]);
}

// ---------------- dtype probe ----------------
__global__ void k_probe(const ushort* __restrict__ x, int* __restrict__ flag){
  __shared__ int red[256];
  int t = threadIdx.x;
  int c = 0;
  for (int j = 0; j < 8; j++){
    ushort u = x[t * 8 + j];
    int e = (u >> 7) & 0xff;
    if (e >= 0x88 || (e != 0 && e <= 0x70)) c++;
  }
  red[t] = c;
  __syncthreads();
  for (int off = 128; off > 0; off >>= 1){
    if (t < off) red[t] += red[t + off];
    __syncthreads();
  }
  if (t == 0) flag[0] = (red[0] > 100) ? 1 : 0;
}

// ---------------- CSR build ----------------
__global__ void k_zero(int* cnt, int* cursor, int* total){
  int i = blockIdx.x * 256 + threadIdx.x;
  if (i < N_NODES){ cnt[i] = 0; cursor[i] = 0; }
  if (i == 0) total[0] = 0;
}

__global__ void k_count(const int* __restrict__ dst, int* __restrict__ cnt){
  int e = blockIdx.x * 256 + threadIdx.x;
  if (e < N_EDGES) atomicAdd(&cnt[dst[e]], 1);
}

// unordered segment allocator: wave scan + 1 atomic per wave (order irrelevant for mean-agg)
__global__ void k_assign(const int* __restrict__ cnt, int* __restrict__ rowstart,
                         int* __restrict__ total){
  int i = blockIdx.x * 256 + threadIdx.x;
  int lane = threadIdx.x & 63;
  int c = (i < N_NODES) ? cnt[i] : 0;
  int scan = c;
  #pragma unroll
  for (int m = 1; m < 64; m <<= 1){
    int v = __shfl_up(scan, m, 64);
    if (lane >= m) scan += v;
  }
  int wave_total = __shfl(scan, 63, 64);
  int base = 0;
  if (lane == 63) base = atomicAdd(total, wave_total);
  base = __shfl(base, 63, 64);
  if (i < N_NODES) rowstart[i] = base + scan - c;
}

__global__ void k_fill(const int* __restrict__ src, const int* __restrict__ dst,
                       const int* __restrict__ rowstart, int* __restrict__ cursor,
                       int* __restrict__ esrc){
  int e = blockIdx.x * 256 + threadIdx.x;
  if (e < N_EDGES){
    int d = dst[e];
    int pos = atomicAdd(&cursor[d], 1);
    esrc[rowstart[d] + pos] = src[e];
  }
}

// ---------------- weight prep (dtype-adaptive) ----------------
__global__ void k_prep_w(const int* __restrict__ flag,
                         const void* __restrict__ W_in,
                         const void* __restrict__ Wl1, const void* __restrict__ Wr1,
                         const void* __restrict__ Wl2, const void* __restrict__ Wr2,
                         ushort* __restrict__ WtA, ushort* __restrict__ Wc1, ushort* __restrict__ Wc2){
  int f32 = flag[0];
  int idx = blockIdx.x * 256 + threadIdx.x;
  if (idx >= 128 * 256) return;
  int n = idx >> 8;
  int k = idx & 255;
  WtA[n * 256 + k] = f2bf(rdany(W_in, k * 128 + n, f32));
  if (k < 128){
    Wc1[n * 256 + k] = f2bf(rdany(Wl1, k * 128 + n, f32));
    Wc2[n * 256 + k] = f2bf(rdany(Wl2, k * 128 + n, f32));
  } else {
    Wc1[n * 256 + k] = f2bf(rdany(Wr1, (k - 128) * 128 + n, f32));
    Wc2[n * 256 + k] = f2bf(rdany(Wr2, (k - 128) * 128 + n, f32));
  }
}

// small vectors -> fp32 staging
__global__ void k_prep_vec(const int* __restrict__ flag,
                           const void* b_in, const void* kind_embed, const void* ext_seed,
                           const void* bl1, const void* gammap, const void* betap,
                           const void* bl2, float* __restrict__ vecs){
  int f32 = flag[0];
  for (int i = threadIdx.x; i < 1152; i += 256){
    float v;
    if (i < 128)       v = rdany(b_in, i, f32);
    else if (i < 512)  v = rdany(kind_embed, i - 128, f32);
    else if (i < 640)  v = rdany(ext_seed, i - 512, f32);
    else if (i < 768)  v = rdany(bl1, i - 640, f32);
    else if (i < 896)  v = rdany(gammap, i - 768, f32);
    else if (i < 1024) v = rdany(betap, i - 896, f32);
    else               v = rdany(bl2, i - 1024, f32);
    vecs[i] = v;
  }
}

// ---------------- input GEMM ----------------
// ILP restructure: preload all 8 A-frags; per K-step batch 8 B-loads into regs
// before the 8 MFMAs. __launch_bounds__(256,2) lifts VGPR cap (compiler chose
// 60 VGPRs before -> one load in flight -> 64 serialized L2 latencies/wave).
__global__ void __launch_bounds__(256, 2) k_gemm_in(
    const int* __restrict__ flag, const void* __restrict__ xin,
    const ushort* __restrict__ WtA, const float* __restrict__ vecs,
    const int* __restrict__ node_kind, ushort* __restrict__ h0){
  int f32 = flag[0];
  int wave = threadIdx.x >> 6;
  int lane = threadIdx.x & 63;
  int quad = lane >> 4;
  int l16  = lane & 15;
  int rb = blockIdx.x * 64 + wave * 16;

  fvec4 acc[8];
  #pragma unroll
  for (int t = 0; t < 8; t++)
    #pragma unroll
    for (int i = 0; i < 4; i++) acc[t][i] = 0.f;

  int arow = rb + l16; if (arow >= N_NODES) arow = N_NODES - 1;
  const ushort* abf = (const ushort*)xin + (size_t)arow * DIN + quad * 8;
  const float*  af  = (const float*)xin + (size_t)arow * DIN + quad * 8;

  bvec8 a[8];
  if (f32){
    #pragma unroll
    for (int k0 = 0; k0 < 8; k0++){
      fvec4 lo = *(const fvec4*)(af + k0 * 32);
      fvec4 hi = *(const fvec4*)(af + k0 * 32 + 4);
      a[k0][0] = (short)f2bf(lo[0]); a[k0][1] = (short)f2bf(lo[1]);
      a[k0][2] = (short)f2bf(lo[2]); a[k0][3] = (short)f2bf(lo[3]);
      a[k0][4] = (short)f2bf(hi[0]); a[k0][5] = (short)f2bf(hi[1]);
      a[k0][6] = (short)f2bf(hi[2]); a[k0][7] = (short)f2bf(hi[3]);
    }
  } else {
    #pragma unroll
    for (int k0 = 0; k0 < 8; k0++) a[k0] = *(const bvec8*)(abf + k0 * 32);
  }

  #pragma unroll
  for (int k0 = 0; k0 < 8; k0++){
    bvec8 bfr[8];
    #pragma unroll
    for (int t = 0; t < 8; t++)
      bfr[t] = *(const bvec8*)(WtA + (t * 16 + l16) * DIN + k0 * 32 + quad * 8);
    #pragma unroll
    for (int t = 0; t < 8; t++)
      acc[t] = __builtin_amdgcn_mfma_f32_16x16x32_bf16(a[k0], bfr[t], acc[t], 0, 0, 0);
  }

  const float* b_in  = vecs;
  const float* kinde = vecs + 128;
  const float* ext   = vecs + 512;
  #pragma unroll
  for (int i = 0; i < 4; i++){
    int row = rb + quad * 4 + i;
    if (row >= N_NODES) continue;
    int kind = node_kind[row];
    float extf = (kind != 0) ? 1.f : 0.f;
    #pragma unroll
    for (int t = 0; t < 8; t++){
      int col = t * 16 + l16;
      float v = acc[t][i] + b_in[col] + kinde[kind * HD + col] + extf * ext[col];
      h0[(size_t)row * HD + col] = f2bf(v);
    }
  }
}

// ---------------- mean aggregation: 4 edge-groups x 16 lanes, 8 rows in flight ----------------
__device__ inline void acc_row(float* acc, uint4 p){
  const uint32_t* pw = (const uint32_t*)&p;
  #pragma unroll
  for (int j = 0; j < 4; j++){
    uint32_t u = pw[j];
    acc[2 * j]     += bf2f((ushort)(u & 0xffffu));
    acc[2 * j + 1] += bf2f((ushort)(u >> 16));
  }
}

__global__ void __launch_bounds__(256) k_gather(
    const ushort* __restrict__ h, const int* __restrict__ rowstart,
    const int* __restrict__ cnt, const int* __restrict__ esrc,
    ushort* __restrict__ agg){
  int n = blockIdx.x * 4 + (threadIdx.x >> 6);
  int lane = threadIdx.x & 63;
  int eg  = lane >> 4;
  int l16 = lane & 15;
  if (n >= N_NODES) return;
  int b = rowstart[n];
  int deg = cnt[n];
  int e = b + deg;

  float acc[8];
  #pragma unroll
  for (int j = 0; j < 8; j++) acc[j] = 0.f;

  for (int i = b; i < e; i += 8){
    int iA = i + eg;
    int iB = i + 4 + eg;
    bool vA = iA < e;
    bool vB = iB < e;
    int last = e - 1;
    int sA = esrc[vA ? iA : last];
    int sB = esrc[vB ? iB : last];
    uint4 pA = {0, 0, 0, 0}, pB = {0, 0, 0, 0};
    if (vA) pA = *(const uint4*)(h + (size_t)sA * HD + l16 * 8);
    if (vB) pB = *(const uint4*)(h + (size_t)sB * HD + l16 * 8);
    acc_row(acc, pA);
    acc_row(acc, pB);
  }

  #pragma unroll
  for (int j = 0; j < 8; j++){
    acc[j] += __shfl_xor(acc[j], 16, 64);
    acc[j] += __shfl_xor(acc[j], 32, 64);
  }

  if (eg == 0){
    float scale = (deg > 0) ? 1.f / (float)deg : 0.f;
    uint4 ov;
    uint32_t* ow = (uint32_t*)&ov;
    #pragma unroll
    for (int j = 0; j < 4; j++){
      ow[j] = (uint32_t)f2bf(acc[2 * j] * scale) |
              ((uint32_t)f2bf(acc[2 * j + 1] * scale) << 16);
    }
    *(uint4*)(agg + (size_t)n * HD + l16 * 8) = ov;
  }
}

// ---------------- conv GEMM (same ILP restructure) ----------------
template<int MODE>
__global__ void __launch_bounds__(256, 2) k_conv(
    const int* __restrict__ flag,
    const ushort* __restrict__ agg, const ushort* __restrict__ h,
    const ushort* __restrict__ Wc, const float* __restrict__ vecs,
    void* __restrict__ outp){
  int f32 = flag[0];
  int wave = threadIdx.x >> 6;
  int lane = threadIdx.x & 63;
  int quad = lane >> 4;
  int l16  = lane & 15;
  int rb = blockIdx.x * 64 + wave * 16;

  fvec4 acc[8];
  #pragma unroll
  for (int t = 0; t < 8; t++)
    #pragma unroll
    for (int i = 0; i < 4; i++) acc[t][i] = 0.f;

  int arow = rb + l16; if (arow >= N_NODES) arow = N_NODES - 1;
  const ushort* aggb = agg + (size_t)arow * HD + quad * 8;
  const ushort* hb   = h   + (size_t)arow * HD + quad * 8;

  bvec8 a[8];
  #pragma unroll
  for (int j = 0; j < 4; j++){
    a[j]     = *(const bvec8*)(aggb + j * 32);
    a[4 + j] = *(const bvec8*)(hb + j * 32);
  }

  #pragma unroll
  for (int k0 = 0; k0 < 8; k0++){
    bvec8 bfr[8];
    #pragma unroll
    for (int t = 0; t < 8; t++)
      bfr[t] = *(const bvec8*)(Wc + (t * 16 + l16) * 256 + k0 * 32 + quad * 8);
    #pragma unroll
    for (int t = 0; t < 8; t++)
      acc[t] = __builtin_amdgcn_mfma_f32_16x16x32_bf16(a[k0], bfr[t], acc[t], 0, 0, 0);
  }

  if (MODE == 1){
    const float* bias   = vecs + 640;
    const float* gammav = vecs + 768;
    const float* betav  = vecs + 896;
    float zv[8][4];
    float s1[4] = {0.f, 0.f, 0.f, 0.f};
    float s2[4] = {0.f, 0.f, 0.f, 0.f};
    #pragma unroll
    for (int t = 0; t < 8; t++){
      float bc = bias[t * 16 + l16];
      #pragma unroll
      for (int i = 0; i < 4; i++){
        float v = acc[t][i] + bc;
        zv[t][i] = v;
        s1[i] += v;
        s2[i] += v * v;
      }
    }
    #pragma unroll
    for (int m = 1; m < 16; m <<= 1){
      #pragma unroll
      for (int i = 0; i < 4; i++){
        s1[i] += __shfl_xor(s1[i], m, 64);
        s2[i] += __shfl_xor(s2[i], m, 64);
      }
    }
    float mu[4], rs[4];
    #pragma unroll
    for (int i = 0; i < 4; i++){
      mu[i] = s1[i] * (1.f / 128.f);
      float var = s2[i] * (1.f / 128.f) - mu[i] * mu[i];
      rs[i] = rsqrtf(var + LN_EPS);
    }
    ushort* ob = (ushort*)outp;
    #pragma unroll
    for (int t = 0; t < 8; t++){
      int col = t * 16 + l16;
      float g = gammav[col], bt = betav[col];
      #pragma unroll
      for (int i = 0; i < 4; i++){
        int row = rb + quad * 4 + i;
        if (row >= N_NODES) continue;
        float v = (zv[t][i] - mu[i]) * rs[i] * g + bt;
        v = fmaxf(v, 0.f);
        ob[(size_t)row * HD + col] = f2bf(v);
      }
    }
  } else {
    const float* bias = vecs + 1024;
    #pragma unroll
    for (int t = 0; t < 8; t++){
      int col = t * 16 + l16;
      float bc = bias[col];
      #pragma unroll
      for (int i = 0; i < 4; i++){
        int row = rb + quad * 4 + i;
        if (row >= N_NODES) continue;
        float v = acc[t][i] + bc;
        if (f32) ((float*)outp)[(size_t)row * HD + col] = v;
        else     ((ushort*)outp)[(size_t)row * HD + col] = f2bf(v);
      }
    }
  }
}

extern "C" void kernel_launch(void* const* d_in, const int* in_sizes, int n_in,
                              void* d_out, int out_size, void* d_ws, size_t ws_size,
                              hipStream_t stream) {
  const void* x          = d_in[0];
  const int*  ei         = (const int*)d_in[1];
  const int*  node_kind  = (const int*)d_in[2];
  const void* W_in       = d_in[3];
  const void* b_in       = d_in[4];
  const void* kind_embed = d_in[5];
  const void* ext_seed   = d_in[6];
  const void* Wl1        = d_in[7];
  const void* bl1        = d_in[8];
  const void* Wr1        = d_in[9];
  const void* gammap     = d_in[10];
  const void* betap      = d_in[11];
  const void* Wl2        = d_in[12];
  const void* bl2        = d_in[13];
  const void* Wr2        = d_in[14];
  const int* src = ei;
  const int* dst = ei + N_EDGES;

  char* ws = (char*)d_ws;
  size_t off = 0;
  auto alloc = [&](size_t bytes) -> void* {
    void* p = ws + off;
    off += (bytes + 255) & ~(size_t)255;
    return p;
  };
  int*    flag     = (int*)alloc(256);
  int*    total    = (int*)alloc(256);
  int*    cnt      = (int*)alloc(N_NODES * 4);
  int*    cursor   = (int*)alloc(N_NODES * 4);
  int*    rowstart = (int*)alloc(N_NODES * 4);
  int*    esrc     = (int*)alloc(N_EDGES * 4);
  ushort* WtA      = (ushort*)alloc(128 * 256 * 2);
  ushort* Wc1      = (ushort*)alloc(128 * 256 * 2);
  ushort* Wc2      = (ushort*)alloc(128 * 256 * 2);
  float*  vecs     = (float*)alloc(1152 * 4);
  ushort* h0       = (ushort*)alloc((size_t)N_NODES * HD * 2);
  ushort* h1       = (ushort*)alloc((size_t)N_NODES * HD * 2);
  ushort* aggb     = (ushort*)alloc((size_t)N_NODES * HD * 2);

  k_probe<<<1, 256, 0, stream>>>((const ushort*)x, flag);
  k_zero<<<(N_NODES + 255) / 256, 256, 0, stream>>>(cnt, cursor, total);
  k_prep_w<<<(128 * 256 + 255) / 256, 256, 0, stream>>>(flag, W_in, Wl1, Wr1, Wl2, Wr2, WtA, Wc1, Wc2);
  k_prep_vec<<<1, 256, 0, stream>>>(flag, b_in, kind_embed, ext_seed, bl1, gammap, betap, bl2, vecs);
  k_count<<<(N_EDGES + 255) / 256, 256, 0, stream>>>(dst, cnt);
  k_assign<<<(N_NODES + 255) / 256, 256, 0, stream>>>(cnt, rowstart, total);
  k_fill<<<(N_EDGES + 255) / 256, 256, 0, stream>>>(src, dst, rowstart, cursor, esrc);

  int gemm_grid = (N_NODES + 63) / 64;
  k_gemm_in<<<gemm_grid, 256, 0, stream>>>(flag, x, WtA, vecs, node_kind, h0);
  k_gather<<<(N_NODES + 3) / 4, 256, 0, stream>>>(h0, rowstart, cnt, esrc, aggb);
  k_conv<1><<<gemm_grid, 256, 0, stream>>>(flag, aggb, h0, Wc1, vecs, (void*)h1);
  k_gather<<<(N_NODES + 3) / 4, 256, 0, stream>>>(h1, rowstart, cnt, esrc, aggb);
  k_conv<2><<<gemm_grid, 256, 0, stream>>>(flag, aggb, h1, Wc2, vecs, d_out);
}

// Round 6
// 301.305 us; speedup vs baseline: 1.6425x; 1.2128x over previous
//
#include <hip/hip_runtime.h>
#include <stdint.h>

#define N_NODES 50000
#define N_EDGES 625000
#define DIN 256
#define HD 128
#define LN_EPS 1e-5f

typedef __attribute__((ext_vector_type(8))) short bvec8;
typedef __attribute__((ext_vector_type(4))) float fvec4;

__device__ inline float bf2f(ushort u){
  union { uint32_t u32; float f; } c; c.u32 = ((uint32_t)u) << 16; return c.f;
}
__device__ inline ushort f2bf(float f){
  union { float f; uint32_t u; } c; c.f = f;
  uint32_t u = c.u;
  return (ushort)((u + 0x7fffu + ((u >> 16) & 1u)) >> 16);
}
__device__ inline float rdany(const void* p, int i, int f32){
  return f32 ? ((const float*)p)[i] : bf2f(((const ushort*)p)[i]);
}

// ---------------- zero + dtype probe (merged) ----------------
__global__ void k_zero_probe(const ushort* __restrict__ x, int* __restrict__ flag,
                             int* cnt, int* cursor, int* total){
  if ((int)blockIdx.x == (int)gridDim.x - 1){
    // probe block: bf16 N(0,1) has sane exponents; fp32 read as ushort doesn't.
    __shared__ int red[256];
    int t = threadIdx.x;
    int c = 0;
    for (int j = 0; j < 8; j++){
      ushort u = x[t * 8 + j];
      int e = (u >> 7) & 0xff;
      if (e >= 0x88 || (e != 0 && e <= 0x70)) c++;
    }
    red[t] = c;
    __syncthreads();
    for (int off = 128; off > 0; off >>= 1){
      if (t < off) red[t] += red[t + off];
      __syncthreads();
    }
    if (t == 0) flag[0] = (red[0] > 100) ? 1 : 0;
    return;
  }
  int i = blockIdx.x * 256 + threadIdx.x;
  if (i < N_NODES){ cnt[i] = 0; cursor[i] = 0; }
  if (i == 0) total[0] = 0;
}

// ---------------- CSR build ----------------
__global__ void k_count(const int* __restrict__ dst, int* __restrict__ cnt){
  int e = blockIdx.x * 256 + threadIdx.x;
  if (e < N_EDGES) atomicAdd(&cnt[dst[e]], 1);
}

// unordered segment allocator: wave scan + 1 atomic per wave (order irrelevant for mean-agg)
__global__ void k_assign(const int* __restrict__ cnt, int* __restrict__ rowstart,
                         int* __restrict__ total){
  int i = blockIdx.x * 256 + threadIdx.x;
  int lane = threadIdx.x & 63;
  int c = (i < N_NODES) ? cnt[i] : 0;
  int scan = c;
  #pragma unroll
  for (int m = 1; m < 64; m <<= 1){
    int v = __shfl_up(scan, m, 64);
    if (lane >= m) scan += v;
  }
  int wave_total = __shfl(scan, 63, 64);
  int base = 0;
  if (lane == 63) base = atomicAdd(total, wave_total);
  base = __shfl(base, 63, 64);
  if (i < N_NODES) rowstart[i] = base + scan - c;
}

__global__ void k_fill(const int* __restrict__ src, const int* __restrict__ dst,
                       const int* __restrict__ rowstart, int* __restrict__ cursor,
                       int* __restrict__ esrc){
  int e = blockIdx.x * 256 + threadIdx.x;
  if (e < N_EDGES){
    int d = dst[e];
    int pos = atomicAdd(&cursor[d], 1);
    esrc[rowstart[d] + pos] = src[e];
  }
}

// ---------------- weight prep: swizzle into MFMA fragment order ----------------
// Layout: chunk c = k0*8 + t (k0 = K-step, t = col-tile); within chunk, lane l's
// 8 elements are B-frag (n = t*16 + (l&15), k = k0*32 + (l>>4)*8 + j).
// => staging loads are lane-consecutive 1KB bursts; ds_read_b128 conflict-free.
__global__ void k_prep_w(const int* __restrict__ flag,
                         const void* __restrict__ W_in,
                         const void* __restrict__ Wl1, const void* __restrict__ Wr1,
                         const void* __restrict__ Wl2, const void* __restrict__ Wr2,
                         ushort* __restrict__ WtA, ushort* __restrict__ Wc1, ushort* __restrict__ Wc2,
                         const void* b_in, const void* kind_embed, const void* ext_seed,
                         const void* bl1, const void* gammap, const void* betap,
                         const void* bl2, float* __restrict__ vecs){
  int f32 = flag[0];
  int idx = blockIdx.x * 256 + threadIdx.x;
  if (idx < 128 * 256){
    int c   = idx >> 9;          // chunk 0..63
    int lam = (idx >> 3) & 63;   // lane
    int j   = idx & 7;
    int k0  = c >> 3;
    int t   = c & 7;
    int n   = t * 16 + (lam & 15);
    int k   = k0 * 32 + (lam >> 4) * 8 + j;
    WtA[idx] = f2bf(rdany(W_in, k * 128 + n, f32));
    if (k < 128){
      Wc1[idx] = f2bf(rdany(Wl1, k * 128 + n, f32));
      Wc2[idx] = f2bf(rdany(Wl2, k * 128 + n, f32));
    } else {
      Wc1[idx] = f2bf(rdany(Wr1, (k - 128) * 128 + n, f32));
      Wc2[idx] = f2bf(rdany(Wr2, (k - 128) * 128 + n, f32));
    }
  }
  if (blockIdx.x == 0){
    for (int i = threadIdx.x; i < 1152; i += 256){
      float v;
      if (i < 128)       v = rdany(b_in, i, f32);
      else if (i < 512)  v = rdany(kind_embed, i - 128, f32);
      else if (i < 640)  v = rdany(ext_seed, i - 512, f32);
      else if (i < 768)  v = rdany(bl1, i - 640, f32);
      else if (i < 896)  v = rdany(gammap, i - 768, f32);
      else if (i < 1024) v = rdany(betap, i - 896, f32);
      else               v = rdany(bl2, i - 1024, f32);
      vecs[i] = v;
    }
  }
}

// ---------------- input GEMM: LDS-staged B, ds_read_b128 K-loop ----------------
__global__ void __launch_bounds__(256) k_gemm_in(
    const int* __restrict__ flag, const void* __restrict__ xin,
    const ushort* __restrict__ WtA, const float* __restrict__ vecs,
    const int* __restrict__ node_kind, ushort* __restrict__ h0){
  __shared__ __align__(16) ushort sW[128 * 256];   // 64 KB
  int f32 = flag[0];
  int tid  = threadIdx.x;
  int wave = tid >> 6;
  int lane = tid & 63;
  int quad = lane >> 4;
  int l16  = lane & 15;
  int rb = blockIdx.x * 64 + wave * 16;

  fvec4 acc[8];
  #pragma unroll
  for (int t = 0; t < 8; t++)
    #pragma unroll
    for (int i = 0; i < 4; i++) acc[t][i] = 0.f;

  int arow = rb + l16; if (arow >= N_NODES) arow = N_NODES - 1;
  const ushort* abf = (const ushort*)xin + (size_t)arow * DIN + quad * 8;
  const float*  af  = (const float*)xin + (size_t)arow * DIN + quad * 8;

  // A fragments (independent HBM loads, all in flight)
  bvec8 a[8];
  if (f32){
    #pragma unroll
    for (int k0 = 0; k0 < 8; k0++){
      fvec4 lo = *(const fvec4*)(af + k0 * 32);
      fvec4 hi = *(const fvec4*)(af + k0 * 32 + 4);
      a[k0][0] = (short)f2bf(lo[0]); a[k0][1] = (short)f2bf(lo[1]);
      a[k0][2] = (short)f2bf(lo[2]); a[k0][3] = (short)f2bf(lo[3]);
      a[k0][4] = (short)f2bf(hi[0]); a[k0][5] = (short)f2bf(hi[1]);
      a[k0][6] = (short)f2bf(hi[2]); a[k0][7] = (short)f2bf(hi[3]);
    }
  } else {
    #pragma unroll
    for (int k0 = 0; k0 < 8; k0++) a[k0] = *(const bvec8*)(abf + k0 * 32);
  }

  // stage swizzled B into LDS: 16 iters x 256 threads x 16B = 64 KB
  #pragma unroll
  for (int it = 0; it < 16; it++){
    int off = it * 2048 + tid * 8;
    *(uint4*)(sW + off) = *(const uint4*)(WtA + off);
  }
  __syncthreads();

  #pragma unroll
  for (int k0 = 0; k0 < 8; k0++){
    #pragma unroll
    for (int t = 0; t < 8; t++){
      bvec8 b = *(const bvec8*)(sW + ((k0 * 8 + t) * 64 + lane) * 8);
      acc[t] = __builtin_amdgcn_mfma_f32_16x16x32_bf16(a[k0], b, acc[t], 0, 0, 0);
    }
  }

  const float* b_in  = vecs;
  const float* kinde = vecs + 128;
  const float* ext   = vecs + 512;
  #pragma unroll
  for (int i = 0; i < 4; i++){
    int row = rb + quad * 4 + i;
    if (row >= N_NODES) continue;
    int kind = node_kind[row];
    float extf = (kind != 0) ? 1.f : 0.f;
    #pragma unroll
    for (int t = 0; t < 8; t++){
      int col = t * 16 + l16;
      float v = acc[t][i] + b_in[col] + kinde[kind * HD + col] + extf * ext[col];
      h0[(size_t)row * HD + col] = f2bf(v);
    }
  }
}

// ---------------- mean aggregation: 4 edge-groups x 16 lanes, 8 rows in flight ----------------
__device__ inline void acc_row(float* acc, uint4 p){
  const uint32_t* pw = (const uint32_t*)&p;
  #pragma unroll
  for (int j = 0; j < 4; j++){
    uint32_t u = pw[j];
    acc[2 * j]     += bf2f((ushort)(u & 0xffffu));
    acc[2 * j + 1] += bf2f((ushort)(u >> 16));
  }
}

__global__ void __launch_bounds__(256) k_gather(
    const ushort* __restrict__ h, const int* __restrict__ rowstart,
    const int* __restrict__ cnt, const int* __restrict__ esrc,
    ushort* __restrict__ agg){
  int n = blockIdx.x * 4 + (threadIdx.x >> 6);
  int lane = threadIdx.x & 63;
  int eg  = lane >> 4;
  int l16 = lane & 15;
  if (n >= N_NODES) return;
  int b = rowstart[n];
  int deg = cnt[n];
  int e = b + deg;

  float acc[8];
  #pragma unroll
  for (int j = 0; j < 8; j++) acc[j] = 0.f;

  for (int i = b; i < e; i += 8){
    int iA = i + eg;
    int iB = i + 4 + eg;
    bool vA = iA < e;
    bool vB = iB < e;
    int last = e - 1;
    int sA = esrc[vA ? iA : last];
    int sB = esrc[vB ? iB : last];
    uint4 pA = {0, 0, 0, 0}, pB = {0, 0, 0, 0};
    if (vA) pA = *(const uint4*)(h + (size_t)sA * HD + l16 * 8);
    if (vB) pB = *(const uint4*)(h + (size_t)sB * HD + l16 * 8);
    acc_row(acc, pA);
    acc_row(acc, pB);
  }

  #pragma unroll
  for (int j = 0; j < 8; j++){
    acc[j] += __shfl_xor(acc[j], 16, 64);
    acc[j] += __shfl_xor(acc[j], 32, 64);
  }

  if (eg == 0){
    float scale = (deg > 0) ? 1.f / (float)deg : 0.f;
    uint4 ov;
    uint32_t* ow = (uint32_t*)&ov;
    #pragma unroll
    for (int j = 0; j < 4; j++){
      ow[j] = (uint32_t)f2bf(acc[2 * j] * scale) |
              ((uint32_t)f2bf(acc[2 * j + 1] * scale) << 16);
    }
    *(uint4*)(agg + (size_t)n * HD + l16 * 8) = ov;
  }
}

// ---------------- conv GEMM: LDS-staged B ----------------
template<int MODE>
__global__ void __launch_bounds__(256) k_conv(
    const int* __restrict__ flag,
    const ushort* __restrict__ agg, const ushort* __restrict__ h,
    const ushort* __restrict__ Wc, const float* __restrict__ vecs,
    void* __restrict__ outp){
  __shared__ __align__(16) ushort sW[128 * 256];   // 64 KB
  int f32 = flag[0];
  int tid  = threadIdx.x;
  int wave = tid >> 6;
  int lane = tid & 63;
  int quad = lane >> 4;
  int l16  = lane & 15;
  int rb = blockIdx.x * 64 + wave * 16;

  fvec4 acc[8];
  #pragma unroll
  for (int t = 0; t < 8; t++)
    #pragma unroll
    for (int i = 0; i < 4; i++) acc[t][i] = 0.f;

  int arow = rb + l16; if (arow >= N_NODES) arow = N_NODES - 1;
  const ushort* aggb = agg + (size_t)arow * HD + quad * 8;
  const ushort* hb   = h   + (size_t)arow * HD + quad * 8;

  // A fragments: k0 0..3 from agg (Wl half), k0 4..7 from h (Wr half)
  bvec8 a[8];
  #pragma unroll
  for (int j = 0; j < 4; j++){
    a[j]     = *(const bvec8*)(aggb + j * 32);
    a[4 + j] = *(const bvec8*)(hb + j * 32);
  }

  #pragma unroll
  for (int it = 0; it < 16; it++){
    int off = it * 2048 + tid * 8;
    *(uint4*)(sW + off) = *(const uint4*)(Wc + off);
  }
  __syncthreads();

  #pragma unroll
  for (int k0 = 0; k0 < 8; k0++){
    #pragma unroll
    for (int t = 0; t < 8; t++){
      bvec8 b = *(const bvec8*)(sW + ((k0 * 8 + t) * 64 + lane) * 8);
      acc[t] = __builtin_amdgcn_mfma_f32_16x16x32_bf16(a[k0], b, acc[t], 0, 0, 0);
    }
  }

  if (MODE == 1){
    const float* bias   = vecs + 640;
    const float* gammav = vecs + 768;
    const float* betav  = vecs + 896;
    float zv[8][4];
    float s1[4] = {0.f, 0.f, 0.f, 0.f};
    float s2[4] = {0.f, 0.f, 0.f, 0.f};
    #pragma unroll
    for (int t = 0; t < 8; t++){
      float bc = bias[t * 16 + l16];
      #pragma unroll
      for (int i = 0; i < 4; i++){
        float v = acc[t][i] + bc;
        zv[t][i] = v;
        s1[i] += v;
        s2[i] += v * v;
      }
    }
    #pragma unroll
    for (int m = 1; m < 16; m <<= 1){
      #pragma unroll
      for (int i = 0; i < 4; i++){
        s1[i] += __shfl_xor(s1[i], m, 64);
        s2[i] += __shfl_xor(s2[i], m, 64);
      }
    }
    float mu[4], rs[4];
    #pragma unroll
    for (int i = 0; i < 4; i++){
      mu[i] = s1[i] * (1.f / 128.f);
      float var = s2[i] * (1.f / 128.f) - mu[i] * mu[i];
      rs[i] = rsqrtf(var + LN_EPS);
    }
    ushort* ob = (ushort*)outp;
    #pragma unroll
    for (int t = 0; t < 8; t++){
      int col = t * 16 + l16;
      float g = gammav[col], bt = betav[col];
      #pragma unroll
      for (int i = 0; i < 4; i++){
        int row = rb + quad * 4 + i;
        if (row >= N_NODES) continue;
        float v = (zv[t][i] - mu[i]) * rs[i] * g + bt;
        v = fmaxf(v, 0.f);
        ob[(size_t)row * HD + col] = f2bf(v);
      }
    }
  } else {
    const float* bias = vecs + 1024;
    #pragma unroll
    for (int t = 0; t < 8; t++){
      int col = t * 16 + l16;
      float bc = bias[col];
      #pragma unroll
      for (int i = 0; i < 4; i++){
        int row = rb + quad * 4 + i;
        if (row >= N_NODES) continue;
        float v = acc[t][i] + bc;
        if (f32) ((float*)outp)[(size_t)row * HD + col] = v;
        else     ((ushort*)outp)[(size_t)row * HD + col] = f2bf(v);
      }
    }
  }
}

extern "C" void kernel_launch(void* const* d_in, const int* in_sizes, int n_in,
                              void* d_out, int out_size, void* d_ws, size_t ws_size,
                              hipStream_t stream) {
  const void* x          = d_in[0];
  const int*  ei         = (const int*)d_in[1];
  const int*  node_kind  = (const int*)d_in[2];
  const void* W_in       = d_in[3];
  const void* b_in       = d_in[4];
  const void* kind_embed = d_in[5];
  const void* ext_seed   = d_in[6];
  const void* Wl1        = d_in[7];
  const void* bl1        = d_in[8];
  const void* Wr1        = d_in[9];
  const void* gammap     = d_in[10];
  const void* betap      = d_in[11];
  const void* Wl2        = d_in[12];
  const void* bl2        = d_in[13];
  const void* Wr2        = d_in[14];
  const int* src = ei;
  const int* dst = ei + N_EDGES;

  char* ws = (char*)d_ws;
  size_t off = 0;
  auto alloc = [&](size_t bytes) -> void* {
    void* p = ws + off;
    off += (bytes + 255) & ~(size_t)255;
    return p;
  };
  int*    flag     = (int*)alloc(256);
  int*    total    = (int*)alloc(256);
  int*    cnt      = (int*)alloc(N_NODES * 4);
  int*    cursor   = (int*)alloc(N_NODES * 4);
  int*    rowstart = (int*)alloc(N_NODES * 4);
  int*    esrc     = (int*)alloc(N_EDGES * 4);
  ushort* WtA      = (ushort*)alloc(128 * 256 * 2);
  ushort* Wc1      = (ushort*)alloc(128 * 256 * 2);
  ushort* Wc2      = (ushort*)alloc(128 * 256 * 2);
  float*  vecs     = (float*)alloc(1152 * 4);
  ushort* h0       = (ushort*)alloc((size_t)N_NODES * HD * 2);
  ushort* h1       = (ushort*)alloc((size_t)N_NODES * HD * 2);
  ushort* aggb     = (ushort*)alloc((size_t)N_NODES * HD * 2);

  k_zero_probe<<<(N_NODES + 255) / 256 + 1, 256, 0, stream>>>((const ushort*)x, flag, cnt, cursor, total);
  k_prep_w<<<(128 * 256 + 255) / 256, 256, 0, stream>>>(flag, W_in, Wl1, Wr1, Wl2, Wr2, WtA, Wc1, Wc2,
                                                        b_in, kind_embed, ext_seed, bl1, gammap, betap, bl2, vecs);
  k_count<<<(N_EDGES + 255) / 256, 256, 0, stream>>>(dst, cnt);
  k_assign<<<(N_NODES + 255) / 256, 256, 0, stream>>>(cnt, rowstart, total);
  k_fill<<<(N_EDGES + 255) / 256, 256, 0, stream>>>(src, dst, rowstart, cursor, esrc);

  int gemm_grid = (N_NODES + 63) / 64;
  k_gemm_in<<<gemm_grid, 256, 0, stream>>>(flag, x, WtA, vecs, node_kind, h0);
  k_gather<<<(N_NODES + 3) / 4, 256, 0, stream>>>(h0, rowstart, cnt, esrc, aggb);
  k_conv<1><<<gemm_grid, 256, 0, stream>>>(flag, aggb, h0, Wc1, vecs, (void*)h1);
  k_gather<<<(N_NODES + 3) / 4, 256, 0, stream>>>(h1, rowstart, cnt, esrc, aggb);
  k_conv<2><<<gemm_grid, 256, 0, stream>>>(flag, aggb, h1, Wc2, vecs, d_out);
}

// Round 7
// 285.448 us; speedup vs baseline: 1.7337x; 1.0556x over previous
//
#include <hip/hip_runtime.h>
#include <stdint.h>

#define N_NODES 50000
#define N_EDGES 625000
#define DIN 256
#define HD 128
#define LN_EPS 1e-5f
#define AGG_STRIDE 136   // 128 + 8 halves pad: spreads LDS banks

typedef __attribute__((ext_vector_type(8))) short bvec8;
typedef __attribute__((ext_vector_type(4))) float fvec4;

__device__ inline float bf2f(ushort u){
  union { uint32_t u32; float f; } c; c.u32 = ((uint32_t)u) << 16; return c.f;
}
__device__ inline ushort f2bf(float f){
  union { float f; uint32_t u; } c; c.f = f;
  uint32_t u = c.u;
  return (ushort)((u + 0x7fffu + ((u >> 16) & 1u)) >> 16);
}
__device__ inline float rdany(const void* p, int i, int f32){
  return f32 ? ((const float*)p)[i] : bf2f(((const ushort*)p)[i]);
}

// ---------------- zero + dtype probe (merged) ----------------
__global__ void k_zero_probe(const ushort* __restrict__ x, int* __restrict__ flag,
                             int* cnt, int* cursor, int* total){
  if ((int)blockIdx.x == (int)gridDim.x - 1){
    __shared__ int red[256];
    int t = threadIdx.x;
    int c = 0;
    for (int j = 0; j < 8; j++){
      ushort u = x[t * 8 + j];
      int e = (u >> 7) & 0xff;
      if (e >= 0x88 || (e != 0 && e <= 0x70)) c++;
    }
    red[t] = c;
    __syncthreads();
    for (int off = 128; off > 0; off >>= 1){
      if (t < off) red[t] += red[t + off];
      __syncthreads();
    }
    if (t == 0) flag[0] = (red[0] > 100) ? 1 : 0;
    return;
  }
  int i = blockIdx.x * 256 + threadIdx.x;
  if (i < N_NODES){ cnt[i] = 0; cursor[i] = 0; }
  if (i == 0) total[0] = 0;
}

// ---------------- CSR build ----------------
__global__ void k_count(const int* __restrict__ dst, int* __restrict__ cnt){
  int e = blockIdx.x * 256 + threadIdx.x;
  if (e < N_EDGES) atomicAdd(&cnt[dst[e]], 1);
}

__global__ void k_assign(const int* __restrict__ cnt, int* __restrict__ rowstart,
                         int* __restrict__ total){
  int i = blockIdx.x * 256 + threadIdx.x;
  int lane = threadIdx.x & 63;
  int c = (i < N_NODES) ? cnt[i] : 0;
  int scan = c;
  #pragma unroll
  for (int m = 1; m < 64; m <<= 1){
    int v = __shfl_up(scan, m, 64);
    if (lane >= m) scan += v;
  }
  int wave_total = __shfl(scan, 63, 64);
  int base = 0;
  if (lane == 63) base = atomicAdd(total, wave_total);
  base = __shfl(base, 63, 64);
  if (i < N_NODES) rowstart[i] = base + scan - c;
}

__global__ void k_fill(const int* __restrict__ src, const int* __restrict__ dst,
                       const int* __restrict__ rowstart, int* __restrict__ cursor,
                       int* __restrict__ esrc){
  int e = blockIdx.x * 256 + threadIdx.x;
  if (e < N_EDGES){
    int d = dst[e];
    int pos = atomicAdd(&cursor[d], 1);
    esrc[rowstart[d] + pos] = src[e];
  }
}

// ---------------- weight prep: swizzle into MFMA fragment order ----------------
// chunk c = k0*8 + t; lane l's 8 elems are B-frag (n = t*16+(l&15), k = k0*32+(l>>4)*8+j)
__global__ void k_prep_w(const int* __restrict__ flag,
                         const void* __restrict__ W_in,
                         const void* __restrict__ Wl1, const void* __restrict__ Wr1,
                         const void* __restrict__ Wl2, const void* __restrict__ Wr2,
                         ushort* __restrict__ WtA, ushort* __restrict__ Wc1, ushort* __restrict__ Wc2,
                         const void* b_in, const void* kind_embed, const void* ext_seed,
                         const void* bl1, const void* gammap, const void* betap,
                         const void* bl2, float* __restrict__ vecs){
  int f32 = flag[0];
  int idx = blockIdx.x * 256 + threadIdx.x;
  if (idx < 128 * 256){
    int c   = idx >> 9;
    int lam = (idx >> 3) & 63;
    int j   = idx & 7;
    int k0  = c >> 3;
    int t   = c & 7;
    int n   = t * 16 + (lam & 15);
    int k   = k0 * 32 + (lam >> 4) * 8 + j;
    WtA[idx] = f2bf(rdany(W_in, k * 128 + n, f32));
    if (k < 128){
      Wc1[idx] = f2bf(rdany(Wl1, k * 128 + n, f32));
      Wc2[idx] = f2bf(rdany(Wl2, k * 128 + n, f32));
    } else {
      Wc1[idx] = f2bf(rdany(Wr1, (k - 128) * 128 + n, f32));
      Wc2[idx] = f2bf(rdany(Wr2, (k - 128) * 128 + n, f32));
    }
  }
  if (blockIdx.x == 0){
    for (int i = threadIdx.x; i < 1152; i += 256){
      float v;
      if (i < 128)       v = rdany(b_in, i, f32);
      else if (i < 512)  v = rdany(kind_embed, i - 128, f32);
      else if (i < 640)  v = rdany(ext_seed, i - 512, f32);
      else if (i < 768)  v = rdany(bl1, i - 640, f32);
      else if (i < 896)  v = rdany(gammap, i - 768, f32);
      else if (i < 1024) v = rdany(betap, i - 896, f32);
      else               v = rdany(bl2, i - 1024, f32);
      vecs[i] = v;
    }
  }
}

// ---------------- input GEMM: LDS-staged B ----------------
__global__ void __launch_bounds__(256) k_gemm_in(
    const int* __restrict__ flag, const void* __restrict__ xin,
    const ushort* __restrict__ WtA, const float* __restrict__ vecs,
    const int* __restrict__ node_kind, ushort* __restrict__ h0){
  __shared__ __align__(16) ushort sW[128 * 256];
  int f32 = flag[0];
  int tid  = threadIdx.x;
  int wave = tid >> 6;
  int lane = tid & 63;
  int quad = lane >> 4;
  int l16  = lane & 15;
  int rb = blockIdx.x * 64 + wave * 16;

  fvec4 acc[8];
  #pragma unroll
  for (int t = 0; t < 8; t++)
    #pragma unroll
    for (int i = 0; i < 4; i++) acc[t][i] = 0.f;

  int arow = rb + l16; if (arow >= N_NODES) arow = N_NODES - 1;
  const ushort* abf = (const ushort*)xin + (size_t)arow * DIN + quad * 8;
  const float*  af  = (const float*)xin + (size_t)arow * DIN + quad * 8;

  bvec8 a[8];
  if (f32){
    #pragma unroll
    for (int k0 = 0; k0 < 8; k0++){
      fvec4 lo = *(const fvec4*)(af + k0 * 32);
      fvec4 hi = *(const fvec4*)(af + k0 * 32 + 4);
      a[k0][0] = (short)f2bf(lo[0]); a[k0][1] = (short)f2bf(lo[1]);
      a[k0][2] = (short)f2bf(lo[2]); a[k0][3] = (short)f2bf(lo[3]);
      a[k0][4] = (short)f2bf(hi[0]); a[k0][5] = (short)f2bf(hi[1]);
      a[k0][6] = (short)f2bf(hi[2]); a[k0][7] = (short)f2bf(hi[3]);
    }
  } else {
    #pragma unroll
    for (int k0 = 0; k0 < 8; k0++) a[k0] = *(const bvec8*)(abf + k0 * 32);
  }

  #pragma unroll
  for (int it = 0; it < 16; it++){
    int off = it * 2048 + tid * 8;
    *(uint4*)(sW + off) = *(const uint4*)(WtA + off);
  }
  __syncthreads();

  #pragma unroll
  for (int k0 = 0; k0 < 8; k0++){
    #pragma unroll
    for (int t = 0; t < 8; t++){
      bvec8 b = *(const bvec8*)(sW + ((k0 * 8 + t) * 64 + lane) * 8);
      acc[t] = __builtin_amdgcn_mfma_f32_16x16x32_bf16(a[k0], b, acc[t], 0, 0, 0);
    }
  }

  const float* b_in  = vecs;
  const float* kinde = vecs + 128;
  const float* ext   = vecs + 512;
  #pragma unroll
  for (int i = 0; i < 4; i++){
    int row = rb + quad * 4 + i;
    if (row >= N_NODES) continue;
    int kind = node_kind[row];
    float extf = (kind != 0) ? 1.f : 0.f;
    #pragma unroll
    for (int t = 0; t < 8; t++){
      int col = t * 16 + l16;
      float v = acc[t][i] + b_in[col] + kinde[kind * HD + col] + extf * ext[col];
      h0[(size_t)row * HD + col] = f2bf(v);
    }
  }
}

// ---------------- fused gather + conv GEMM ----------------
// Phase 1: gather this block's 64 agg rows into LDS (4 nodes/wave in parallel,
//          4 rows in flight per node). Phase 2: A-frags to regs, then re-use
//          the same 32KB LDS for the weights in two half-stages.
template<int MODE>
__global__ void __launch_bounds__(256) k_conv_fused(
    const int* __restrict__ flag, const ushort* __restrict__ h,
    const int* __restrict__ rowstart, const int* __restrict__ cnt,
    const int* __restrict__ esrc,
    const ushort* __restrict__ Wc, const float* __restrict__ vecs,
    void* __restrict__ outp){
  __shared__ __align__(16) ushort sbuf[16384];   // 32 KB: agg(8704) then weights(16384)
  int f32 = flag[0];
  int tid  = threadIdx.x;
  int wave = tid >> 6;
  int lane = tid & 63;
  int quad = lane >> 4;
  int l16  = lane & 15;
  int rb0 = blockIdx.x * 64;
  int rb  = rb0 + wave * 16;

  // self-row (h-half) A-frags: issue global loads early
  int arow = rb + l16; if (arow >= N_NODES) arow = N_NODES - 1;
  const ushort* hb = h + (size_t)arow * HD + quad * 8;
  bvec8 a[8];
  #pragma unroll
  for (int j = 0; j < 4; j++) a[4 + j] = *(const bvec8*)(hb + j * 32);

  // ---- phase 1: gather agg rows into LDS ----
  int eg = quad;  // node selector within round
  #pragma unroll
  for (int r = 0; r < 4; r++){
    int nd = wave * 16 + r * 4 + eg;     // node within block (0..63)
    int n  = rb0 + nd;
    bool valid = n < N_NODES;
    int b   = valid ? rowstart[n] : 0;
    int deg = valid ? cnt[n] : 0;
    int e   = b + deg;
    float acc[8];
    #pragma unroll
    for (int j = 0; j < 8; j++) acc[j] = 0.f;
    for (int i = b; i < e; i += 4){
      int i1 = i + 1, i2 = i + 2, i3 = i + 3;
      bool v1 = i1 < e, v2 = i2 < e, v3 = i3 < e;
      int s0 = esrc[i];
      int s1 = esrc[v1 ? i1 : i];
      int s2 = esrc[v2 ? i2 : i];
      int s3 = esrc[v3 ? i3 : i];
      uint4 p0 = *(const uint4*)(h + (size_t)s0 * HD + l16 * 8);
      uint4 p1 = {0,0,0,0}, p2 = {0,0,0,0}, p3 = {0,0,0,0};
      if (v1) p1 = *(const uint4*)(h + (size_t)s1 * HD + l16 * 8);
      if (v2) p2 = *(const uint4*)(h + (size_t)s2 * HD + l16 * 8);
      if (v3) p3 = *(const uint4*)(h + (size_t)s3 * HD + l16 * 8);
      const uint32_t* w0 = (const uint32_t*)&p0;
      const uint32_t* w1 = (const uint32_t*)&p1;
      const uint32_t* w2 = (const uint32_t*)&p2;
      const uint32_t* w3 = (const uint32_t*)&p3;
      #pragma unroll
      for (int j = 0; j < 4; j++){
        acc[2*j]   += bf2f((ushort)(w0[j] & 0xffffu)) + bf2f((ushort)(w1[j] & 0xffffu))
                    + bf2f((ushort)(w2[j] & 0xffffu)) + bf2f((ushort)(w3[j] & 0xffffu));
        acc[2*j+1] += bf2f((ushort)(w0[j] >> 16)) + bf2f((ushort)(w1[j] >> 16))
                    + bf2f((ushort)(w2[j] >> 16)) + bf2f((ushort)(w3[j] >> 16));
      }
    }
    float scale = (deg > 0) ? 1.f / (float)deg : 0.f;
    ushort* dstp = sbuf + nd * AGG_STRIDE + l16 * 8;
    #pragma unroll
    for (int j = 0; j < 8; j++) dstp[j] = f2bf(acc[j] * scale);
  }
  __syncthreads();

  // ---- A-frags (agg half) from LDS ----
  {
    int nd = wave * 16 + l16;
    const ushort* ap = sbuf + nd * AGG_STRIDE + quad * 8;
    #pragma unroll
    for (int j = 0; j < 4; j++) a[j] = *(const bvec8*)(ap + j * 32);
  }
  __syncthreads();   // everyone done reading agg before overwrite

  fvec4 acc[8];
  #pragma unroll
  for (int t = 0; t < 8; t++)
    #pragma unroll
    for (int i = 0; i < 4; i++) acc[t][i] = 0.f;

  // ---- weights in two 32KB half-stages over the same LDS ----
  #pragma unroll
  for (int s = 0; s < 2; s++){
    #pragma unroll
    for (int it = 0; it < 8; it++){
      int off = it * 2048 + tid * 8;
      *(uint4*)(sbuf + off) = *(const uint4*)(Wc + s * 16384 + off);
    }
    __syncthreads();
    #pragma unroll
    for (int k0 = 0; k0 < 4; k0++){
      #pragma unroll
      for (int t = 0; t < 8; t++){
        bvec8 b = *(const bvec8*)(sbuf + ((k0 * 8 + t) * 64 + lane) * 8);
        acc[t] = __builtin_amdgcn_mfma_f32_16x16x32_bf16(a[s * 4 + k0], b, acc[t], 0, 0, 0);
      }
    }
    __syncthreads();
  }

  if (MODE == 1){
    const float* bias   = vecs + 640;
    const float* gammav = vecs + 768;
    const float* betav  = vecs + 896;
    float zv[8][4];
    float s1[4] = {0.f, 0.f, 0.f, 0.f};
    float s2[4] = {0.f, 0.f, 0.f, 0.f};
    #pragma unroll
    for (int t = 0; t < 8; t++){
      float bc = bias[t * 16 + l16];
      #pragma unroll
      for (int i = 0; i < 4; i++){
        float v = acc[t][i] + bc;
        zv[t][i] = v;
        s1[i] += v;
        s2[i] += v * v;
      }
    }
    #pragma unroll
    for (int m = 1; m < 16; m <<= 1){
      #pragma unroll
      for (int i = 0; i < 4; i++){
        s1[i] += __shfl_xor(s1[i], m, 64);
        s2[i] += __shfl_xor(s2[i], m, 64);
      }
    }
    float mu[4], rs[4];
    #pragma unroll
    for (int i = 0; i < 4; i++){
      mu[i] = s1[i] * (1.f / 128.f);
      float var = s2[i] * (1.f / 128.f) - mu[i] * mu[i];
      rs[i] = rsqrtf(var + LN_EPS);
    }
    ushort* ob = (ushort*)outp;
    #pragma unroll
    for (int t = 0; t < 8; t++){
      int col = t * 16 + l16;
      float g = gammav[col], bt = betav[col];
      #pragma unroll
      for (int i = 0; i < 4; i++){
        int row = rb + quad * 4 + i;
        if (row >= N_NODES) continue;
        float v = (zv[t][i] - mu[i]) * rs[i] * g + bt;
        v = fmaxf(v, 0.f);
        ob[(size_t)row * HD + col] = f2bf(v);
      }
    }
  } else {
    const float* bias = vecs + 1024;
    #pragma unroll
    for (int t = 0; t < 8; t++){
      int col = t * 16 + l16;
      float bc = bias[col];
      #pragma unroll
      for (int i = 0; i < 4; i++){
        int row = rb + quad * 4 + i;
        if (row >= N_NODES) continue;
        float v = acc[t][i] + bc;
        if (f32) ((float*)outp)[(size_t)row * HD + col] = v;
        else     ((ushort*)outp)[(size_t)row * HD + col] = f2bf(v);
      }
    }
  }
}

extern "C" void kernel_launch(void* const* d_in, const int* in_sizes, int n_in,
                              void* d_out, int out_size, void* d_ws, size_t ws_size,
                              hipStream_t stream) {
  const void* x          = d_in[0];
  const int*  ei         = (const int*)d_in[1];
  const int*  node_kind  = (const int*)d_in[2];
  const void* W_in       = d_in[3];
  const void* b_in       = d_in[4];
  const void* kind_embed = d_in[5];
  const void* ext_seed   = d_in[6];
  const void* Wl1        = d_in[7];
  const void* bl1        = d_in[8];
  const void* Wr1        = d_in[9];
  const void* gammap     = d_in[10];
  const void* betap      = d_in[11];
  const void* Wl2        = d_in[12];
  const void* bl2        = d_in[13];
  const void* Wr2        = d_in[14];
  const int* src = ei;
  const int* dst = ei + N_EDGES;

  char* ws = (char*)d_ws;
  size_t off = 0;
  auto alloc = [&](size_t bytes) -> void* {
    void* p = ws + off;
    off += (bytes + 255) & ~(size_t)255;
    return p;
  };
  int*    flag     = (int*)alloc(256);
  int*    total    = (int*)alloc(256);
  int*    cnt      = (int*)alloc(N_NODES * 4);
  int*    cursor   = (int*)alloc(N_NODES * 4);
  int*    rowstart = (int*)alloc(N_NODES * 4);
  int*    esrc     = (int*)alloc(N_EDGES * 4);
  ushort* WtA      = (ushort*)alloc(128 * 256 * 2);
  ushort* Wc1      = (ushort*)alloc(128 * 256 * 2);
  ushort* Wc2      = (ushort*)alloc(128 * 256 * 2);
  float*  vecs     = (float*)alloc(1152 * 4);
  ushort* h0       = (ushort*)alloc((size_t)N_NODES * HD * 2);
  ushort* h1       = (ushort*)alloc((size_t)N_NODES * HD * 2);

  k_zero_probe<<<(N_NODES + 255) / 256 + 1, 256, 0, stream>>>((const ushort*)x, flag, cnt, cursor, total);
  k_prep_w<<<(128 * 256 + 255) / 256, 256, 0, stream>>>(flag, W_in, Wl1, Wr1, Wl2, Wr2, WtA, Wc1, Wc2,
                                                        b_in, kind_embed, ext_seed, bl1, gammap, betap, bl2, vecs);
  k_count<<<(N_EDGES + 255) / 256, 256, 0, stream>>>(dst, cnt);
  k_assign<<<(N_NODES + 255) / 256, 256, 0, stream>>>(cnt, rowstart, total);
  k_fill<<<(N_EDGES + 255) / 256, 256, 0, stream>>>(src, dst, rowstart, cursor, esrc);

  int gemm_grid = (N_NODES + 63) / 64;
  k_gemm_in<<<gemm_grid, 256, 0, stream>>>(flag, x, WtA, vecs, node_kind, h0);
  k_conv_fused<1><<<gemm_grid, 256, 0, stream>>>(flag, h0, rowstart, cnt, esrc, Wc1, vecs, (void*)h1);
  k_conv_fused<2><<<gemm_grid, 256, 0, stream>>>(flag, h1, rowstart, cnt, esrc, Wc2, vecs, d_out);
}